// Round 1
// baseline (1203.668 us; speedup 1.0000x reference)
//
#include <hip/hip_runtime.h>
#include <math.h>

// EnhancedSTGCNLayer: x[T,N,64] -> tconv(k=3)+LN+ReLU+res -> GCNConv(softmax ew, self loops) -> [T,N,128]
#define N_NODES 20000
#define E_EDGES 160000
#define T_STEPS 8
#define C_IN    64
#define C_OUT   128

// ---------------- reduction helpers (256-thread blocks = 4 waves) ----------------
__device__ __forceinline__ float wredSum(float v) {
#pragma unroll
  for (int d = 32; d > 0; d >>= 1) v += __shfl_xor(v, d, 64);
  return v;
}
__device__ __forceinline__ float wredMax(float v) {
#pragma unroll
  for (int d = 32; d > 0; d >>= 1) v = fmaxf(v, __shfl_xor(v, d, 64));
  return v;
}
__device__ __forceinline__ float bredSum(float v, float* sm4) {
  __syncthreads();
  v = wredSum(v);
  const int lane = threadIdx.x & 63, wid = threadIdx.x >> 6;
  if (lane == 0) sm4[wid] = v;
  __syncthreads();
  return sm4[0] + sm4[1] + sm4[2] + sm4[3];
}
__device__ __forceinline__ float bredMax(float v, float* sm4) {
  __syncthreads();
  v = wredMax(v);
  const int lane = threadIdx.x & 63, wid = threadIdx.x >> 6;
  if (lane == 0) sm4[wid] = v;
  __syncthreads();
  return fmaxf(fmaxf(sm4[0], sm4[1]), fmaxf(sm4[2], sm4[3]));
}

// ---------------- edge-weight softmax stats ----------------
__global__ __launch_bounds__(256) void k_pmax(const float* __restrict__ w, float* __restrict__ pm) {
  __shared__ float sm4[4];
  float m = -3.4e38f;
  for (int i = blockIdx.x * 256 + threadIdx.x; i < E_EDGES; i += 256 * 256) m = fmaxf(m, w[i]);
  m = bredMax(m, sm4);
  if (threadIdx.x == 0) pm[blockIdx.x] = m;
}

__global__ __launch_bounds__(256) void k_sumexp(const float* __restrict__ w, const float* __restrict__ pm,
                                                float* __restrict__ ps) {
  __shared__ float sm4[4];
  const float mx = bredMax(pm[threadIdx.x], sm4);
  float s = 0.f;
  for (int i = blockIdx.x * 256 + threadIdx.x; i < E_EDGES; i += 256 * 256) s += expf(w[i] - mx);
  s = bredSum(s, sm4);
  if (threadIdx.x == 0) ps[blockIdx.x] = s;
}

__global__ __launch_bounds__(256) void k_init(float* __restrict__ deg, int* __restrict__ cnt) {
  const int i = blockIdx.x * 256 + threadIdx.x;
  if (i < N_NODES) { deg[i] = 1.0f; cnt[i] = 0; }
}

// per-edge: softmax weight, degree accumulation (dest), in-degree count
__global__ __launch_bounds__(256) void k_edge(const float* __restrict__ w, const int* __restrict__ ei,
                                              const float* __restrict__ pm, const float* __restrict__ ps,
                                              float* __restrict__ ewv, float* __restrict__ deg,
                                              int* __restrict__ cnt) {
  __shared__ float sm4[4];
  const float mx  = bredMax(pm[threadIdx.x], sm4);
  const float sum = bredSum(ps[threadIdx.x], sm4);
  const int e = blockIdx.x * 256 + threadIdx.x;  // grid = E/256 exact
  const float v = expf(w[e] - mx) / sum;
  ewv[e] = v;
  const int c = ei[E_EDGES + e];
  atomicAdd(&deg[c], v);
  atomicAdd(&cnt[c], 1);
}

__global__ __launch_bounds__(256) void k_dinv(const float* __restrict__ deg, float* __restrict__ dinv) {
  const int i = blockIdx.x * 256 + threadIdx.x;
  if (i < N_NODES) dinv[i] = rsqrtf(deg[i]);  // deg >= 1 always (self loop)
}

// single-block exclusive scan of cnt[N] -> off[N+1]; cursor = off copy
__global__ __launch_bounds__(256) void k_scan(const int* __restrict__ cnt, int* __restrict__ off,
                                              int* __restrict__ cursor) {
  __shared__ int wpart[4];
  __shared__ int s_carry;
  const int tid = threadIdx.x, lane = tid & 63, wid = tid >> 6;
  if (tid == 0) s_carry = 0;
  __syncthreads();
  for (int base = 0; base < N_NODES; base += 256) {
    const int i = base + tid;
    const int v = (i < N_NODES) ? cnt[i] : 0;
    int s = v;  // inclusive wave scan
#pragma unroll
    for (int d = 1; d < 64; d <<= 1) { const int u = __shfl_up(s, d, 64); if (lane >= d) s += u; }
    if (lane == 63) wpart[wid] = s;
    const int carry = s_carry;
    __syncthreads();
    int add = 0;
#pragma unroll
    for (int wv = 0; wv < 4; ++wv) if (wv < wid) add += wpart[wv];
    if (i < N_NODES) { const int excl = carry + add + (s - v); off[i] = excl; cursor[i] = excl; }
    __syncthreads();
    if (tid == 255) s_carry = carry + add + s;
    __syncthreads();
  }
  if (threadIdx.x == 0) off[N_NODES] = E_EDGES;
}

// per-edge: sym-norm coefficient + CSR scatter by destination
__global__ __launch_bounds__(256) void k_norm_scatter(const int* __restrict__ ei, const float* __restrict__ ewv,
                                                      const float* __restrict__ dinv, int* __restrict__ cursor,
                                                      float* __restrict__ normv, int* __restrict__ eidx) {
  const int e = blockIdx.x * 256 + threadIdx.x;  // grid = E/256 exact
  const int r = ei[e], c = ei[E_EDGES + e];
  normv[e] = dinv[r] * ewv[e] * dinv[c];
  const int pos = atomicAdd(&cursor[c], 1);
  eidx[pos] = e;
}

// ---------------- fused node transform: tconv + LN + ReLU + residual -> xcmb[N,T,128] ----------------
// threads: o = tid&127 (output channel), kh = tid>>7 (K-half). Weights stay in VGPRs;
// x row addresses are wave-uniform (no threadIdx) -> scalar loads feeding v_fmac s-operand.
#define NPB 32
__global__ __launch_bounds__(256) void k_node(const float* __restrict__ x,
                                              const float* __restrict__ tconv_w, const float* __restrict__ tconv_b,
                                              const float* __restrict__ ln_g, const float* __restrict__ ln_b,
                                              const float* __restrict__ res_w, const float* __restrict__ res_b,
                                              float* __restrict__ xcmb) {
  const int tid = threadIdx.x;
  const int o = tid & 127, kh = tid >> 7;
  const int t = blockIdx.y;
  const int n0 = blockIdx.x * NPB;

  // edge-tap masks folded into the weights (zero-pad in time)
  const float mm = (t > 0) ? 1.f : 0.f;
  const float mp = (t < T_STEPS - 1) ? 1.f : 0.f;

  float wc[96], wr[32];
#pragma unroll
  for (int j = 0; j < 32; ++j) {
    wc[j * 3 + 0] = tconv_w[o * 192 + kh * 96 + j * 3 + 0] * mm;
    wc[j * 3 + 1] = tconv_w[o * 192 + kh * 96 + j * 3 + 1];
    wc[j * 3 + 2] = tconv_w[o * 192 + kh * 96 + j * 3 + 2] * mp;
  }
#pragma unroll
  for (int j = 0; j < 32; ++j) wr[j] = res_w[o * 64 + kh * 32 + j];
  const float cb = tconv_b[o], rb = res_b[o], gg = ln_g[o], bb = ln_b[o];

  const int tm = (t > 0) ? t - 1 : 0;             // clamped (masked weights make it a no-op)
  const int tp = (t < T_STEPS - 1) ? t + 1 : t;
  const float* xmb = x + ((size_t)tm * N_NODES) * C_IN + kh * 32;
  const float* x0b = x + ((size_t)t  * N_NODES) * C_IN + kh * 32;
  const float* xpb = x + ((size_t)tp * N_NODES) * C_IN + kh * 32;

  __shared__ float pcA[256], prA[256], swrk[8];

  for (int i = 0; i < NPB; ++i) {
    const int n = n0 + i;
    const float* xm = xmb + (size_t)n * C_IN;
    const float* x0 = x0b + (size_t)n * C_IN;
    const float* xp = xpb + (size_t)n * C_IN;
    float pc = 0.f, pr = 0.f;
#pragma unroll
    for (int j = 0; j < 32; ++j) {
      const float xa = xm[j], xb = x0[j], xd = xp[j];
      pc = fmaf(xa, wc[j * 3 + 0], pc);
      pc = fmaf(xb, wc[j * 3 + 1], pc);
      pc = fmaf(xd, wc[j * 3 + 2], pc);
      pr = fmaf(xb, wr[j], pr);
    }
    pcA[tid] = pc; prA[tid] = pr;
    __syncthreads();
    float h = 0.f, r = 0.f, v = 0.f, v2 = 0.f;
    if (kh == 0) {
      h = pcA[o] + pcA[o + 128] + cb;
      r = prA[o] + prA[o + 128] + rb;
      v = h; v2 = h * h;
    }
#pragma unroll
    for (int d = 32; d > 0; d >>= 1) { v += __shfl_xor(v, d, 64); v2 += __shfl_xor(v2, d, 64); }
    const int wid = tid >> 6, lane = tid & 63;
    if (lane == 0) { swrk[wid * 2] = v; swrk[wid * 2 + 1] = v2; }
    __syncthreads();
    if (kh == 0) {
      const float mu  = (swrk[0] + swrk[2]) * (1.f / 128.f);
      const float ms  = (swrk[1] + swrk[3]) * (1.f / 128.f);
      const float var = ms - mu * mu;
      float xc = (h - mu) * rsqrtf(var + 1e-5f) * gg + bb;
      xc = fmaxf(xc, 0.f) + r;
      xcmb[((size_t)n * T_STEPS + t) * C_OUT + o] = xc;
    }
    __syncthreads();
  }
}

// ---------------- GCN linear: xt = xcmb @ gcn_w^T, in-place over xcmb ----------------
#define RPB 32
__global__ __launch_bounds__(256) void k_xt(float* __restrict__ xcmb, const float* __restrict__ gcn_w) {
  const int tid = threadIdx.x, o = tid & 127, kh = tid >> 7;
  float wg[64];
#pragma unroll
  for (int j = 0; j < 64; ++j) wg[j] = gcn_w[o * 128 + kh * 64 + j];
  __shared__ float pA[256];
  const size_t r0 = (size_t)blockIdx.x * RPB;
  for (int i = 0; i < RPB; ++i) {
    const float* a = xcmb + (r0 + i) * C_OUT + kh * 64;
    float p = 0.f;
#pragma unroll
    for (int j = 0; j < 64; ++j) p = fmaf(a[j], wg[j], p);
    pA[tid] = p;
    __syncthreads();  // all reads of this row done -> safe in-place write
    if (kh == 0) xcmb[(r0 + i) * C_OUT + o] = pA[o] + pA[o + 128];
    __syncthreads();  // pA reuse
  }
}

// ---------------- CSR aggregation + bias + ReLU -> out[T,N,128] ----------------
#define NPB_AGG 4
__global__ __launch_bounds__(256) void k_agg(const float* __restrict__ xt, const int* __restrict__ ei,
                                             const float* __restrict__ normv, const int* __restrict__ off,
                                             const int* __restrict__ eidx, const float* __restrict__ dinv,
                                             const float* __restrict__ gcn_b, float* __restrict__ out) {
  const int tid = threadIdx.x, o = tid & 127, th = tid >> 7;
  const float b = gcn_b[o];
  for (int jj = 0; jj < NPB_AGG; ++jj) {
    const int j = blockIdx.x * NPB_AGG + jj;
    const int s = off[j], e = off[j + 1];
    const float d2 = dinv[j] * dinv[j];
    float acc[4];
#pragma unroll
    for (int i = 0; i < 4; ++i)
      acc[i] = d2 * xt[((size_t)j * T_STEPS + th * 4 + i) * C_OUT + o];
    for (int k = s; k < e; ++k) {
      const int eid = eidx[k];
      const int r = ei[eid];          // source node (uniform across block)
      const float nm = normv[eid];
#pragma unroll
      for (int i = 0; i < 4; ++i)
        acc[i] = fmaf(nm, xt[((size_t)r * T_STEPS + th * 4 + i) * C_OUT + o], acc[i]);
    }
#pragma unroll
    for (int i = 0; i < 4; ++i)
      out[((size_t)(th * 4 + i) * N_NODES + j) * C_OUT + o] = fmaxf(acc[i] + b, 0.f);
  }
}

// ---------------- host ----------------
extern "C" void kernel_launch(void* const* d_in, const int* in_sizes, int n_in,
                              void* d_out, int out_size, void* d_ws, size_t ws_size,
                              hipStream_t stream) {
  (void)in_sizes; (void)n_in; (void)out_size; (void)ws_size;
  const float* x       = (const float*)d_in[0];
  const int*   ei      = (const int*)d_in[1];
  const float* ewt     = (const float*)d_in[2];
  const float* tconv_w = (const float*)d_in[3];
  const float* tconv_b = (const float*)d_in[4];
  const float* ln_g    = (const float*)d_in[5];
  const float* ln_b    = (const float*)d_in[6];
  const float* res_w   = (const float*)d_in[7];
  const float* res_b   = (const float*)d_in[8];
  const float* gcn_w   = (const float*)d_in[9];
  const float* gcn_b   = (const float*)d_in[10];
  float* out = (float*)d_out;

  // workspace carve (~84 MB)
  float* wsf   = (float*)d_ws;
  float* xcmb  = wsf;                                   // N*T*128 (xt written in-place)
  float* ewv   = xcmb + (size_t)N_NODES * T_STEPS * C_OUT;  // E
  float* normv = ewv + E_EDGES;                         // E
  float* deg   = normv + E_EDGES;                       // N
  float* dinv  = deg + N_NODES;                         // N
  float* pm    = dinv + N_NODES;                        // 256
  float* ps    = pm + 256;                              // 256
  int*   cnt    = (int*)(ps + 256);                     // N
  int*   off    = cnt + N_NODES;                        // N+1
  int*   cursor = off + N_NODES + 1;                    // N
  int*   eidx   = cursor + N_NODES;                     // E

  const int nblk = (N_NODES + 255) / 256;               // 79
  const int eblk = E_EDGES / 256;                       // 625 exact

  k_init<<<nblk, 256, 0, stream>>>(deg, cnt);
  k_pmax<<<256, 256, 0, stream>>>(ewt, pm);
  k_sumexp<<<256, 256, 0, stream>>>(ewt, pm, ps);
  k_edge<<<eblk, 256, 0, stream>>>(ewt, ei, pm, ps, ewv, deg, cnt);
  k_dinv<<<nblk, 256, 0, stream>>>(deg, dinv);
  k_scan<<<1, 256, 0, stream>>>(cnt, off, cursor);
  k_norm_scatter<<<eblk, 256, 0, stream>>>(ei, ewv, dinv, cursor, normv, eidx);

  k_node<<<dim3(N_NODES / NPB, T_STEPS), 256, 0, stream>>>(x, tconv_w, tconv_b, ln_g, ln_b,
                                                           res_w, res_b, xcmb);
  k_xt<<<(N_NODES * T_STEPS) / RPB, 256, 0, stream>>>(xcmb, gcn_w);
  k_agg<<<N_NODES / NPB_AGG, 256, 0, stream>>>(xcmb, ei, normv, off, eidx, dinv, gcn_b, out);
}

// Round 2
// 1170.107 us; speedup vs baseline: 1.0287x; 1.0287x over previous
//
#include <hip/hip_runtime.h>
#include <math.h>

// EnhancedSTGCNLayer: x[T,N,64] -> tconv(k=3)+LN+ReLU+res -> GCNConv(softmax ew, self loops) -> [T,N,128]
#define N_NODES 20000
#define E_EDGES 160000
#define T_STEPS 8
#define C_IN    64
#define C_OUT   128

// ---------------- reduction helpers (256-thread blocks = 4 waves) ----------------
__device__ __forceinline__ float wredSum(float v) {
#pragma unroll
  for (int d = 32; d > 0; d >>= 1) v += __shfl_xor(v, d, 64);
  return v;
}
__device__ __forceinline__ float wredMax(float v) {
#pragma unroll
  for (int d = 32; d > 0; d >>= 1) v = fmaxf(v, __shfl_xor(v, d, 64));
  return v;
}
__device__ __forceinline__ float bredSum(float v, float* sm4) {
  __syncthreads();
  v = wredSum(v);
  const int lane = threadIdx.x & 63, wid = threadIdx.x >> 6;
  if (lane == 0) sm4[wid] = v;
  __syncthreads();
  return sm4[0] + sm4[1] + sm4[2] + sm4[3];
}
__device__ __forceinline__ float bredMax(float v, float* sm4) {
  __syncthreads();
  v = wredMax(v);
  const int lane = threadIdx.x & 63, wid = threadIdx.x >> 6;
  if (lane == 0) sm4[wid] = v;
  __syncthreads();
  return fmaxf(fmaxf(sm4[0], sm4[1]), fmaxf(sm4[2], sm4[3]));
}

// ---------------- edge-weight softmax stats ----------------
__global__ __launch_bounds__(256) void k_pmax(const float* __restrict__ w, float* __restrict__ pm) {
  __shared__ float sm4[4];
  float m = -3.4e38f;
  for (int i = blockIdx.x * 256 + threadIdx.x; i < E_EDGES; i += 256 * 256) m = fmaxf(m, w[i]);
  m = bredMax(m, sm4);
  if (threadIdx.x == 0) pm[blockIdx.x] = m;
}

__global__ __launch_bounds__(256) void k_sumexp(const float* __restrict__ w, const float* __restrict__ pm,
                                                float* __restrict__ ps) {
  __shared__ float sm4[4];
  const float mx = bredMax(pm[threadIdx.x], sm4);
  float s = 0.f;
  for (int i = blockIdx.x * 256 + threadIdx.x; i < E_EDGES; i += 256 * 256) s += expf(w[i] - mx);
  s = bredSum(s, sm4);
  if (threadIdx.x == 0) ps[blockIdx.x] = s;
}

__global__ __launch_bounds__(256) void k_init(float* __restrict__ deg, int* __restrict__ cnt) {
  const int i = blockIdx.x * 256 + threadIdx.x;
  if (i < N_NODES) { deg[i] = 1.0f; cnt[i] = 0; }
}

// per-edge: softmax weight, degree accumulation (dest), in-degree count
__global__ __launch_bounds__(256) void k_edge(const float* __restrict__ w, const int* __restrict__ ei,
                                              const float* __restrict__ pm, const float* __restrict__ ps,
                                              float* __restrict__ ewv, float* __restrict__ deg,
                                              int* __restrict__ cnt) {
  __shared__ float sm4[4];
  const float mx  = bredMax(pm[threadIdx.x], sm4);
  const float sum = bredSum(ps[threadIdx.x], sm4);
  const int e = blockIdx.x * 256 + threadIdx.x;  // grid = E/256 exact
  const float v = expf(w[e] - mx) / sum;
  ewv[e] = v;
  const int c = ei[E_EDGES + e];
  atomicAdd(&deg[c], v);
  atomicAdd(&cnt[c], 1);
}

__global__ __launch_bounds__(256) void k_dinv(const float* __restrict__ deg, float* __restrict__ dinv) {
  const int i = blockIdx.x * 256 + threadIdx.x;
  if (i < N_NODES) dinv[i] = rsqrtf(deg[i]);  // deg >= 1 always (self loop)
}

// single-block exclusive scan of cnt[N] -> off[N+1]; cursor = off copy
__global__ __launch_bounds__(256) void k_scan(const int* __restrict__ cnt, int* __restrict__ off,
                                              int* __restrict__ cursor) {
  __shared__ int wpart[4];
  __shared__ int s_carry;
  const int tid = threadIdx.x, lane = tid & 63, wid = tid >> 6;
  if (tid == 0) s_carry = 0;
  __syncthreads();
  for (int base = 0; base < N_NODES; base += 256) {
    const int i = base + tid;
    const int v = (i < N_NODES) ? cnt[i] : 0;
    int s = v;  // inclusive wave scan
#pragma unroll
    for (int d = 1; d < 64; d <<= 1) { const int u = __shfl_up(s, d, 64); if (lane >= d) s += u; }
    if (lane == 63) wpart[wid] = s;
    const int carry = s_carry;
    __syncthreads();
    int add = 0;
#pragma unroll
    for (int wv = 0; wv < 4; ++wv) if (wv < wid) add += wpart[wv];
    if (i < N_NODES) { const int excl = carry + add + (s - v); off[i] = excl; cursor[i] = excl; }
    __syncthreads();
    if (tid == 255) s_carry = carry + add + s;
    __syncthreads();
  }
  if (threadIdx.x == 0) off[N_NODES] = E_EDGES;
}

// per-edge: sym-norm coefficient + CSR scatter by destination
__global__ __launch_bounds__(256) void k_norm_scatter(const int* __restrict__ ei, const float* __restrict__ ewv,
                                                      const float* __restrict__ dinv, int* __restrict__ cursor,
                                                      float* __restrict__ normv, int* __restrict__ eidx) {
  const int e = blockIdx.x * 256 + threadIdx.x;  // grid = E/256 exact
  const int r = ei[e], c = ei[E_EDGES + e];
  normv[e] = dinv[r] * ewv[e] * dinv[c];
  const int pos = atomicAdd(&cursor[c], 1);
  eidx[pos] = e;
}

// ---------------- fused node transform + GCN linear ----------------
// tconv(k=3)+LN+ReLU+res -> (in LDS) -> xt = row @ gcn_w^T -> global xt[N,T,128]
// 512 threads: o = tid&127 (output channel), kq = tid>>7 (K-quarter).
// Weights resident in VGPRs: conv 48 + res 16 + gcn 32 = 96 floats/thread.
// TILE=16 rows/block, batched 4 rows per barrier phase (5 barriers / 4 rows).
#define TILE_N 16
__global__ __launch_bounds__(512) void k_node_fused(const float* __restrict__ x,
                                                    const float* __restrict__ tconv_w, const float* __restrict__ tconv_b,
                                                    const float* __restrict__ ln_g, const float* __restrict__ ln_b,
                                                    const float* __restrict__ res_w, const float* __restrict__ res_b,
                                                    const float* __restrict__ gcn_w, float* __restrict__ xt) {
  const int tid = threadIdx.x;
  const int o = tid & 127, kq = tid >> 7;        // kq wave-uniform (tid>>7; wave = 64 lanes)
  const int t = blockIdx.y;
  const int n0 = blockIdx.x * TILE_N;

  // temporal zero-pad masks folded into conv weights
  const float mm = (t > 0) ? 1.f : 0.f;
  const float mp = (t < T_STEPS - 1) ? 1.f : 0.f;

  float wc[48], wr[16], wg[32];
#pragma unroll
  for (int j = 0; j < 16; ++j) {
    wc[j * 3 + 0] = tconv_w[o * 192 + (kq * 16 + j) * 3 + 0] * mm;
    wc[j * 3 + 1] = tconv_w[o * 192 + (kq * 16 + j) * 3 + 1];
    wc[j * 3 + 2] = tconv_w[o * 192 + (kq * 16 + j) * 3 + 2] * mp;
  }
#pragma unroll
  for (int j = 0; j < 16; ++j) wr[j] = res_w[o * 64 + kq * 16 + j];
#pragma unroll
  for (int j = 0; j < 32; ++j) wg[j] = gcn_w[o * 128 + kq * 32 + j];
  const float cb = tconv_b[o], rb = res_b[o], gg = ln_g[o], bb = ln_b[o];

  const int tm = (t > 0) ? t - 1 : 0;            // clamped; masked weights zero the tap
  const int tp = (t < T_STEPS - 1) ? t + 1 : t;
  const float* xmb = x + ((size_t)tm * N_NODES) * C_IN + kq * 16;
  const float* x0b = x + ((size_t)t  * N_NODES) * C_IN + kq * 16;
  const float* xpb = x + ((size_t)tp * N_NODES) * C_IN + kq * 16;

  __shared__ __align__(16) float plc[4 * 4 * 128];   // [kq][r][o] conv partials
  __shared__ __align__(16) float plr[4 * 4 * 128];   // [kq][r][o] res partials (then unused)
  __shared__ __align__(16) float rowl[4][128];       // LN'd rows for gcn broadcast
  __shared__ float s_ws[8][2];                       // per-wave LN sums

  const int lane = tid & 63, wv = tid >> 6;
  const int rr = tid >> 7;                           // combine-phase row (== kq numerically)

  for (int b = 0; b < TILE_N / 4; ++b) {
    __syncthreads();                                 // protect LDS reuse across batches
    // ---- phase A: conv + res partials for 4 rows ----
    float pc[4], pr[4];
#pragma unroll
    for (int r = 0; r < 4; ++r) {
      const size_t n = (size_t)(n0 + b * 4 + r);
      const float4* xm4 = (const float4*)(xmb + n * C_IN);
      const float4* x04 = (const float4*)(x0b + n * C_IN);
      const float4* xp4 = (const float4*)(xpb + n * C_IN);
      float apc = 0.f, apr = 0.f;
#pragma unroll
      for (int j = 0; j < 4; ++j) {
        const float4 a = xm4[j], c0 = x04[j], d = xp4[j];
        const float* ap = (const float*)&a;
        const float* cp = (const float*)&c0;
        const float* dp = (const float*)&d;
#pragma unroll
        for (int u = 0; u < 4; ++u) {
          const int ch = j * 4 + u;
          apc = fmaf(ap[u], wc[ch * 3 + 0], apc);
          apc = fmaf(cp[u], wc[ch * 3 + 1], apc);
          apc = fmaf(dp[u], wc[ch * 3 + 2], apc);
          apr = fmaf(cp[u], wr[ch], apr);
        }
      }
      pc[r] = apc; pr[r] = apr;
    }
#pragma unroll
    for (int r = 0; r < 4; ++r) {
      plc[kq * 512 + r * 128 + o] = pc[r];
      plr[kq * 512 + r * 128 + o] = pr[r];
    }
    __syncthreads();

    // ---- phase B: combine partials + LayerNorm + ReLU + residual ----
    float h = plc[0 * 512 + rr * 128 + o] + plc[1 * 512 + rr * 128 + o] +
              plc[2 * 512 + rr * 128 + o] + plc[3 * 512 + rr * 128 + o] + cb;
    float rv = plr[0 * 512 + rr * 128 + o] + plr[1 * 512 + rr * 128 + o] +
               plr[2 * 512 + rr * 128 + o] + plr[3 * 512 + rr * 128 + o] + rb;
    float v = h, v2 = h * h;
#pragma unroll
    for (int d = 32; d > 0; d >>= 1) { v += __shfl_xor(v, d, 64); v2 += __shfl_xor(v2, d, 64); }
    if (lane == 0) { s_ws[wv][0] = v; s_ws[wv][1] = v2; }
    __syncthreads();
    {
      const int wbase = (rr << 1);                   // waves 2rr, 2rr+1 hold row rr
      const float sv  = s_ws[wbase][0] + s_ws[wbase + 1][0];
      const float sv2 = s_ws[wbase][1] + s_ws[wbase + 1][1];
      const float mu  = sv * (1.f / 128.f);
      const float var = sv2 * (1.f / 128.f) - mu * mu;
      float xc = (h - mu) * rsqrtf(var + 1e-5f) * gg + bb;
      xc = fmaxf(xc, 0.f) + rv;
      rowl[rr][o] = xc;
    }
    __syncthreads();

    // ---- phase C: gcn linear partials, rows broadcast from LDS ----
#pragma unroll
    for (int r = 0; r < 4; ++r) {
      const float4* rw = (const float4*)(&rowl[r][kq * 32]);
      float pg = 0.f;
#pragma unroll
      for (int j = 0; j < 8; ++j) {
        const float4 a = rw[j];
        const float* ap = (const float*)&a;
#pragma unroll
        for (int u = 0; u < 4; ++u) pg = fmaf(ap[u], wg[j * 4 + u], pg);
      }
      pc[r] = pg;
    }
    __syncthreads();                                 // phase-B plc reads done before overwrite
#pragma unroll
    for (int r = 0; r < 4; ++r) plc[kq * 512 + r * 128 + o] = pc[r];
    __syncthreads();

    // ---- phase D: combine + store xt ----
    {
      const float s = plc[0 * 512 + rr * 128 + o] + plc[1 * 512 + rr * 128 + o] +
                      plc[2 * 512 + rr * 128 + o] + plc[3 * 512 + rr * 128 + o];
      const size_t n = (size_t)(n0 + b * 4 + rr);
      xt[(n * T_STEPS + t) * C_OUT + o] = s;
    }
  }
}

// ---------------- CSR aggregation + bias + ReLU -> out[T,N,128] ----------------
#define NPB_AGG 4
__global__ __launch_bounds__(256) void k_agg(const float* __restrict__ xt, const int* __restrict__ ei,
                                             const float* __restrict__ normv, const int* __restrict__ off,
                                             const int* __restrict__ eidx, const float* __restrict__ dinv,
                                             const float* __restrict__ gcn_b, float* __restrict__ out) {
  const int tid = threadIdx.x, o = tid & 127, th = tid >> 7;
  const float b = gcn_b[o];
  for (int jj = 0; jj < NPB_AGG; ++jj) {
    const int j = blockIdx.x * NPB_AGG + jj;
    const int s = off[j], e = off[j + 1];
    const float d2 = dinv[j] * dinv[j];
    float acc[4];
#pragma unroll
    for (int i = 0; i < 4; ++i)
      acc[i] = d2 * xt[((size_t)j * T_STEPS + th * 4 + i) * C_OUT + o];
    for (int k = s; k < e; ++k) {
      const int eid = eidx[k];
      const int r = ei[eid];          // source node (uniform across block)
      const float nm = normv[eid];
#pragma unroll
      for (int i = 0; i < 4; ++i)
        acc[i] = fmaf(nm, xt[((size_t)r * T_STEPS + th * 4 + i) * C_OUT + o], acc[i]);
    }
#pragma unroll
    for (int i = 0; i < 4; ++i)
      out[((size_t)(th * 4 + i) * N_NODES + j) * C_OUT + o] = fmaxf(acc[i] + b, 0.f);
  }
}

// ---------------- host ----------------
extern "C" void kernel_launch(void* const* d_in, const int* in_sizes, int n_in,
                              void* d_out, int out_size, void* d_ws, size_t ws_size,
                              hipStream_t stream) {
  (void)in_sizes; (void)n_in; (void)out_size; (void)ws_size;
  const float* x       = (const float*)d_in[0];
  const int*   ei      = (const int*)d_in[1];
  const float* ewt     = (const float*)d_in[2];
  const float* tconv_w = (const float*)d_in[3];
  const float* tconv_b = (const float*)d_in[4];
  const float* ln_g    = (const float*)d_in[5];
  const float* ln_b    = (const float*)d_in[6];
  const float* res_w   = (const float*)d_in[7];
  const float* res_b   = (const float*)d_in[8];
  const float* gcn_w   = (const float*)d_in[9];
  const float* gcn_b   = (const float*)d_in[10];
  float* out = (float*)d_out;

  // workspace carve (~84 MB)
  float* wsf   = (float*)d_ws;
  float* xt    = wsf;                                   // N*T*128
  float* ewv   = xt + (size_t)N_NODES * T_STEPS * C_OUT;  // E
  float* normv = ewv + E_EDGES;                         // E
  float* deg   = normv + E_EDGES;                       // N
  float* dinv  = deg + N_NODES;                         // N
  float* pm    = dinv + N_NODES;                        // 256
  float* ps    = pm + 256;                              // 256
  int*   cnt    = (int*)(ps + 256);                     // N
  int*   off    = cnt + N_NODES;                        // N+1
  int*   cursor = off + N_NODES + 1;                    // N
  int*   eidx   = cursor + N_NODES;                     // E

  const int nblk = (N_NODES + 255) / 256;               // 79
  const int eblk = E_EDGES / 256;                       // 625 exact

  k_init<<<nblk, 256, 0, stream>>>(deg, cnt);
  k_pmax<<<256, 256, 0, stream>>>(ewt, pm);
  k_sumexp<<<256, 256, 0, stream>>>(ewt, pm, ps);
  k_edge<<<eblk, 256, 0, stream>>>(ewt, ei, pm, ps, ewv, deg, cnt);
  k_dinv<<<nblk, 256, 0, stream>>>(deg, dinv);
  k_scan<<<1, 256, 0, stream>>>(cnt, off, cursor);
  k_norm_scatter<<<eblk, 256, 0, stream>>>(ei, ewv, dinv, cursor, normv, eidx);

  k_node_fused<<<dim3(N_NODES / TILE_N, T_STEPS), 512, 0, stream>>>(
      x, tconv_w, tconv_b, ln_g, ln_b, res_w, res_b, gcn_w, xt);
  k_agg<<<N_NODES / NPB_AGG, 256, 0, stream>>>(xt, ei, normv, off, eidx, dinv, gcn_b, out);
}

// Round 3
// 296.154 us; speedup vs baseline: 4.0643x; 3.9510x over previous
//
#include <hip/hip_runtime.h>
#include <math.h>

// EnhancedSTGCNLayer: x[T,N,64] -> tconv(k=3)+LN+ReLU+res -> GCNConv(softmax ew, self loops) -> [T,N,128]
#define N_NODES 20000
#define E_EDGES 160000
#define T_STEPS 8
#define C_IN    64
#define C_OUT   128

typedef __bf16 bf16x8 __attribute__((ext_vector_type(8)));
typedef float  f32x4  __attribute__((ext_vector_type(4)));
#define MFMA16(a, b, c) __builtin_amdgcn_mfma_f32_16x16x32_bf16((a), (b), (c), 0, 0, 0)

__device__ __forceinline__ unsigned short f2u(float f) {
  __bf16 b = (__bf16)f;                       // RNE fp32->bf16
  return __builtin_bit_cast(unsigned short, b);
}
__device__ __forceinline__ unsigned int pack2(float lo, float hi) {
  return (unsigned int)f2u(lo) | ((unsigned int)f2u(hi) << 16);
}

// ---------------- reduction helpers ----------------
__device__ __forceinline__ float wredSum(float v) {
#pragma unroll
  for (int d = 32; d > 0; d >>= 1) v += __shfl_xor(v, d, 64);
  return v;
}
__device__ __forceinline__ float wredMax(float v) {
#pragma unroll
  for (int d = 32; d > 0; d >>= 1) v = fmaxf(v, __shfl_xor(v, d, 64));
  return v;
}
__device__ __forceinline__ float bredSum(float v, float* sm4) {
  __syncthreads();
  v = wredSum(v);
  const int lane = threadIdx.x & 63, wid = threadIdx.x >> 6;
  if (lane == 0) sm4[wid] = v;
  __syncthreads();
  return sm4[0] + sm4[1] + sm4[2] + sm4[3];
}
__device__ __forceinline__ float bredMax(float v, float* sm4) {
  __syncthreads();
  v = wredMax(v);
  const int lane = threadIdx.x & 63, wid = threadIdx.x >> 6;
  if (lane == 0) sm4[wid] = v;
  __syncthreads();
  return fmaxf(fmaxf(sm4[0], sm4[1]), fmaxf(sm4[2], sm4[3]));
}

// ---------------- edge-weight softmax stats ----------------
__global__ __launch_bounds__(256) void k_pmax(const float* __restrict__ w, float* __restrict__ pm) {
  __shared__ float sm4[4];
  float m = -3.4e38f;
  for (int i = blockIdx.x * 256 + threadIdx.x; i < E_EDGES; i += 256 * 256) m = fmaxf(m, w[i]);
  m = bredMax(m, sm4);
  if (threadIdx.x == 0) pm[blockIdx.x] = m;
}

__global__ __launch_bounds__(256) void k_sumexp(const float* __restrict__ w, const float* __restrict__ pm,
                                                float* __restrict__ ps) {
  __shared__ float sm4[4];
  const float mx = bredMax(pm[threadIdx.x], sm4);
  float s = 0.f;
  for (int i = blockIdx.x * 256 + threadIdx.x; i < E_EDGES; i += 256 * 256) s += expf(w[i] - mx);
  s = bredSum(s, sm4);
  if (threadIdx.x == 0) ps[blockIdx.x] = s;
}

__global__ __launch_bounds__(256) void k_init(float* __restrict__ deg, int* __restrict__ cnt) {
  const int i = blockIdx.x * 256 + threadIdx.x;
  if (i < N_NODES) { deg[i] = 1.0f; cnt[i] = 0; }
}

__global__ __launch_bounds__(256) void k_edge(const float* __restrict__ w, const int* __restrict__ ei,
                                              const float* __restrict__ pm, const float* __restrict__ ps,
                                              float* __restrict__ ewv, float* __restrict__ deg,
                                              int* __restrict__ cnt) {
  __shared__ float sm4[4];
  const float mx  = bredMax(pm[threadIdx.x], sm4);
  const float sum = bredSum(ps[threadIdx.x], sm4);
  const int e = blockIdx.x * 256 + threadIdx.x;  // grid = E/256 exact
  const float v = expf(w[e] - mx) / sum;
  ewv[e] = v;
  const int c = ei[E_EDGES + e];
  atomicAdd(&deg[c], v);
  atomicAdd(&cnt[c], 1);
}

__global__ __launch_bounds__(256) void k_dinv(const float* __restrict__ deg, float* __restrict__ dinv) {
  const int i = blockIdx.x * 256 + threadIdx.x;
  if (i < N_NODES) dinv[i] = rsqrtf(deg[i]);
}

// single-block exclusive scan of cnt[N] -> off[N+1]; cursor = off copy
__global__ __launch_bounds__(256) void k_scan(const int* __restrict__ cnt, int* __restrict__ off,
                                              int* __restrict__ cursor) {
  __shared__ int wpart[4];
  __shared__ int s_carry;
  const int tid = threadIdx.x, lane = tid & 63, wid = tid >> 6;
  if (tid == 0) s_carry = 0;
  __syncthreads();
  for (int base = 0; base < N_NODES; base += 256) {
    const int i = base + tid;
    const int v = (i < N_NODES) ? cnt[i] : 0;
    int s = v;
#pragma unroll
    for (int d = 1; d < 64; d <<= 1) { const int u = __shfl_up(s, d, 64); if (lane >= d) s += u; }
    if (lane == 63) wpart[wid] = s;
    const int carry = s_carry;
    __syncthreads();
    int add = 0;
#pragma unroll
    for (int wv = 0; wv < 4; ++wv) if (wv < wid) add += wpart[wv];
    if (i < N_NODES) { const int excl = carry + add + (s - v); off[i] = excl; cursor[i] = excl; }
    __syncthreads();
    if (tid == 255) s_carry = carry + add + s;
    __syncthreads();
  }
  if (threadIdx.x == 0) off[N_NODES] = E_EDGES;
}

__global__ __launch_bounds__(256) void k_norm_scatter(const int* __restrict__ ei, const float* __restrict__ ewv,
                                                      const float* __restrict__ dinv, int* __restrict__ cursor,
                                                      float* __restrict__ normv, int* __restrict__ eidx) {
  const int e = blockIdx.x * 256 + threadIdx.x;
  const int r = ei[e], c = ei[E_EDGES + e];
  normv[e] = dinv[r] * ewv[e] * dinv[c];
  const int pos = atomicAdd(&cursor[c], 1);
  eidx[pos] = e;
}

// ---------------- weight prep: pack B matrices into MFMA fragment order (bf16 pairs) ----------------
// word layout (u32): conv [0,12288): ((ks*8+ct)*64+l)*4+reg, k=ks*32+(l>>4)*8+reg*2, o=ct*16+(l&15)
//                    res  [12288,16384): ks2 in 0..1, k in [0,64)
//                    gcn  [16384,24576): ks in 0..3, k in [0,128)
__global__ __launch_bounds__(256) void k_wprep(const float* __restrict__ tconv_w, const float* __restrict__ res_w,
                                               const float* __restrict__ gcn_w, unsigned int* __restrict__ Bf) {
  const int gid = blockIdx.x * 256 + threadIdx.x;  // 96 blocks * 256 = 24576 exact
  float v0, v1;
  if (gid < 12288) {
    const int reg = gid & 3, l = (gid >> 2) & 63, ct = (gid >> 8) & 7, ks = gid >> 11;
    const int o = ct * 16 + (l & 15);
    const int k0 = ks * 32 + ((l >> 4) & 3) * 8 + reg * 2;
    const int c0 = k0 & 63, tap0 = k0 >> 6;
    const int c1 = (k0 + 1) & 63, tap1 = (k0 + 1) >> 6;
    v0 = tconv_w[o * 192 + c0 * 3 + tap0];
    v1 = tconv_w[o * 192 + c1 * 3 + tap1];
  } else if (gid < 16384) {
    const int g = gid - 12288;
    const int reg = g & 3, l = (g >> 2) & 63, ct = (g >> 8) & 7, ks = g >> 11;
    const int o = ct * 16 + (l & 15);
    const int k0 = ks * 32 + ((l >> 4) & 3) * 8 + reg * 2;
    v0 = res_w[o * 64 + k0];
    v1 = res_w[o * 64 + k0 + 1];
  } else {
    const int g = gid - 16384;
    const int reg = g & 3, l = (g >> 2) & 63, ct = (g >> 8) & 7, ks = g >> 11;
    const int o = ct * 16 + (l & 15);
    const int k0 = ks * 32 + ((l >> 4) & 3) * 8 + reg * 2;
    v0 = gcn_w[o * 128 + k0];
    v1 = gcn_w[o * 128 + k0 + 1];
  }
  Bf[gid] = pack2(v0, v1);
}

// ---------------- node transform via MFMA: tconv + LN + ReLU + res -> xcmb fp32 ----------------
// block: 128 rows (fixed t), 256 threads = 4 waves, wave w owns output cols [32w, 32w+32)
#define AS_STRIDE 200  // bf16 units; 400B row stride: 16B-aligned frags, conflict-free b128 reads
__global__ __launch_bounds__(256) void k_node_mfma(const float* __restrict__ x,
                                                   const float* __restrict__ tconv_b,
                                                   const float* __restrict__ ln_g, const float* __restrict__ ln_b,
                                                   const float* __restrict__ res_b,
                                                   const unsigned int* __restrict__ Bf,
                                                   float* __restrict__ xcmb) {
  const int tid = threadIdx.x, lane = tid & 63, w = tid >> 6;
  const int l15 = lane & 15, lg = lane >> 4;
  const int t = blockIdx.y;
  const int n0 = blockIdx.x * 128;

  __shared__ unsigned short As[128 * AS_STRIDE];
  __shared__ float psum[4][64], psq[4][64], smu[64], srs[64];

  // ---- stage A-tile: [row][tap*64+c] bf16, zero-padded taps at t edges ----
#pragma unroll
  for (int tap = 0; tap < 3; ++tap) {
    const int tq = t + tap - 1;
    const int valid = (tq >= 0 && tq < T_STEPS);
#pragma unroll
    for (int p = 0; p < 8; ++p) {
      const int chunk = p * 256 + tid;          // 2048 = 128 rows * 16 float4
      const int row = chunk >> 4, c4 = chunk & 15;
      int n = n0 + row; n = (n < N_NODES) ? n : (N_NODES - 1);
      float4 v = make_float4(0.f, 0.f, 0.f, 0.f);
      if (valid) v = *(const float4*)(x + ((size_t)tq * N_NODES + n) * C_IN + c4 * 4);
      uint2 pk;
      pk.x = pack2(v.x, v.y);
      pk.y = pack2(v.z, v.w);
      *(uint2*)&As[row * AS_STRIDE + tap * 64 + c4 * 4] = pk;
    }
  }

  // ---- B fragments (resident in VGPRs) ----
  const uint4* Bf4 = (const uint4*)Bf;
  uint4 Bc[2][6], Br[2][2];
#pragma unroll
  for (int ct = 0; ct < 2; ++ct) {
    const int ctg = w * 2 + ct;
#pragma unroll
    for (int ks = 0; ks < 6; ++ks) Bc[ct][ks] = Bf4[(ks * 8 + ctg) * 64 + lane];
#pragma unroll
    for (int ks = 0; ks < 2; ++ks) Br[ct][ks] = Bf4[3072 + (ks * 8 + ctg) * 64 + lane];
  }
  float cb[2], rb[2], gv[2], bv[2];
#pragma unroll
  for (int ct = 0; ct < 2; ++ct) {
    const int col = w * 32 + ct * 16 + l15;
    cb[ct] = tconv_b[col]; rb[ct] = res_b[col]; gv[ct] = ln_g[col]; bv[ct] = ln_b[col];
  }
  __syncthreads();

  // ---- two halves of 64 rows ----
#pragma unroll
  for (int h = 0; h < 2; ++h) {
    f32x4 accC[4][2], accR[4][2];
#pragma unroll
    for (int rt = 0; rt < 4; ++rt)
#pragma unroll
      for (int ct = 0; ct < 2; ++ct) { accC[rt][ct] = (f32x4)0.f; accR[rt][ct] = (f32x4)0.f; }

#pragma unroll
    for (int ks = 0; ks < 6; ++ks) {
      bf16x8 af[4];
#pragma unroll
      for (int rt = 0; rt < 4; ++rt)
        af[rt] = *(const bf16x8*)&As[(h * 64 + rt * 16 + l15) * AS_STRIDE + ks * 32 + lg * 8];
#pragma unroll
      for (int rt = 0; rt < 4; ++rt)
#pragma unroll
        for (int ct = 0; ct < 2; ++ct)
          accC[rt][ct] = MFMA16(af[rt], __builtin_bit_cast(bf16x8, Bc[ct][ks]), accC[rt][ct]);
      if (ks == 2 || ks == 3) {  // middle tap (k 64..127) drives the 1x1 residual conv
#pragma unroll
        for (int rt = 0; rt < 4; ++rt)
#pragma unroll
          for (int ct = 0; ct < 2; ++ct)
            accR[rt][ct] = MFMA16(af[rt], __builtin_bit_cast(bf16x8, Br[ct][ks - 2]), accR[rt][ct]);
      }
    }

    // ---- LayerNorm stats (rows in C-layout: row=(lane>>4)*4+j, col=16*ct+l15) ----
#pragma unroll
    for (int rt = 0; rt < 4; ++rt) {
      float s[4], s2[4];
#pragma unroll
      for (int j = 0; j < 4; ++j) {
        const float h0 = accC[rt][0][j] + cb[0];
        const float h1 = accC[rt][1][j] + cb[1];
        accC[rt][0][j] = h0; accC[rt][1][j] = h1;
        s[j] = h0 + h1; s2[j] = h0 * h0 + h1 * h1;
      }
#pragma unroll
      for (int d = 1; d < 16; d <<= 1)
#pragma unroll
        for (int j = 0; j < 4; ++j) { s[j] += __shfl_xor(s[j], d, 64); s2[j] += __shfl_xor(s2[j], d, 64); }
      if (l15 == 0)
#pragma unroll
        for (int j = 0; j < 4; ++j) {
          psum[w][rt * 16 + lg * 4 + j] = s[j];
          psq[w][rt * 16 + lg * 4 + j] = s2[j];
        }
    }
    __syncthreads();
    if (tid < 64) {
      const float S  = psum[0][tid] + psum[1][tid] + psum[2][tid] + psum[3][tid];
      const float S2 = psq[0][tid] + psq[1][tid] + psq[2][tid] + psq[3][tid];
      const float mu = S * (1.f / 128.f);
      const float var = S2 * (1.f / 128.f) - mu * mu;
      smu[tid] = mu; srs[tid] = rsqrtf(var + 1e-5f);
    }
    __syncthreads();

    // ---- apply LN + ReLU + residual, store fp32 ----
#pragma unroll
    for (int rt = 0; rt < 4; ++rt)
#pragma unroll
      for (int j = 0; j < 4; ++j) {
        const int row64 = rt * 16 + lg * 4 + j;
        const float mu = smu[row64], rs = srs[row64];
        const int n = n0 + h * 64 + row64;
        if (n < N_NODES) {
#pragma unroll
          for (int ct = 0; ct < 2; ++ct) {
            float xc = (accC[rt][ct][j] - mu) * rs * gv[ct] + bv[ct];
            xc = fmaxf(xc, 0.f) + accR[rt][ct][j] + rb[ct];
            xcmb[((size_t)t * N_NODES + n) * C_OUT + w * 32 + ct * 16 + l15] = xc;
          }
        }
      }
    __syncthreads();  // protect psum/smu reuse for next half
  }
}

// ---------------- GCN linear via MFMA: xt[n][t][o] = xcmb[t][n][:] @ gcn_w^T ----------------
#define AS2_STRIDE 136
__global__ __launch_bounds__(256) void k_xt_mfma(const float* __restrict__ xcmb,
                                                 const unsigned int* __restrict__ Bf,
                                                 float* __restrict__ xt) {
  const int tid = threadIdx.x, lane = tid & 63, w = tid >> 6;
  const int l15 = lane & 15, lg = lane >> 4;
  const size_t R0 = (size_t)blockIdx.x * 128;   // flat row = t*N + n; 1250 blocks exact

  __shared__ unsigned short As[128 * AS2_STRIDE];
#pragma unroll
  for (int p = 0; p < 16; ++p) {
    const int chunk = p * 256 + tid;            // 4096 = 128 rows * 32 float4
    const int row = chunk >> 5, c4 = chunk & 31;
    const float4 v = *(const float4*)(xcmb + (R0 + row) * C_OUT + c4 * 4);
    uint2 pk; pk.x = pack2(v.x, v.y); pk.y = pack2(v.z, v.w);
    *(uint2*)&As[row * AS2_STRIDE + c4 * 4] = pk;
  }
  const uint4* Bf4 = (const uint4*)Bf;
  uint4 Bg[2][4];
#pragma unroll
  for (int ct = 0; ct < 2; ++ct)
#pragma unroll
    for (int ks = 0; ks < 4; ++ks) Bg[ct][ks] = Bf4[4096 + (ks * 8 + (w * 2 + ct)) * 64 + lane];
  __syncthreads();

  f32x4 acc[8][2];
#pragma unroll
  for (int rt = 0; rt < 8; ++rt)
#pragma unroll
    for (int ct = 0; ct < 2; ++ct) acc[rt][ct] = (f32x4)0.f;

#pragma unroll
  for (int ks = 0; ks < 4; ++ks) {
    bf16x8 af[8];
#pragma unroll
    for (int rt = 0; rt < 8; ++rt)
      af[rt] = *(const bf16x8*)&As[(rt * 16 + l15) * AS2_STRIDE + ks * 32 + lg * 8];
#pragma unroll
    for (int rt = 0; rt < 8; ++rt)
#pragma unroll
      for (int ct = 0; ct < 2; ++ct)
        acc[rt][ct] = MFMA16(af[rt], __builtin_bit_cast(bf16x8, Bg[ct][ks]), acc[rt][ct]);
  }

  // store to [n][t][o] (k_agg's gather-friendly layout)
#pragma unroll
  for (int rt = 0; rt < 8; ++rt)
#pragma unroll
    for (int j = 0; j < 4; ++j) {
      const size_t fr = R0 + rt * 16 + lg * 4 + j;     // t*N + n
      const int tt = (int)(fr / N_NODES);
      const int nn = (int)(fr - (size_t)tt * N_NODES);
#pragma unroll
      for (int ct = 0; ct < 2; ++ct)
        xt[((size_t)nn * T_STEPS + tt) * C_OUT + w * 32 + ct * 16 + l15] = acc[rt][ct][j];
    }
}

// ---------------- CSR aggregation + bias + ReLU -> out[T,N,128] ----------------
#define NPB_AGG 4
__global__ __launch_bounds__(256) void k_agg(const float* __restrict__ xt, const int* __restrict__ ei,
                                             const float* __restrict__ normv, const int* __restrict__ off,
                                             const int* __restrict__ eidx, const float* __restrict__ dinv,
                                             const float* __restrict__ gcn_b, float* __restrict__ out) {
  const int tid = threadIdx.x, o = tid & 127, th = tid >> 7;
  const float b = gcn_b[o];
  for (int jj = 0; jj < NPB_AGG; ++jj) {
    const int j = blockIdx.x * NPB_AGG + jj;
    const int s = off[j], e = off[j + 1];
    const float d2 = dinv[j] * dinv[j];
    float acc[4];
#pragma unroll
    for (int i = 0; i < 4; ++i)
      acc[i] = d2 * xt[((size_t)j * T_STEPS + th * 4 + i) * C_OUT + o];
    for (int k = s; k < e; ++k) {
      const int eid = eidx[k];
      const int r = ei[eid];
      const float nm = normv[eid];
#pragma unroll
      for (int i = 0; i < 4; ++i)
        acc[i] = fmaf(nm, xt[((size_t)r * T_STEPS + th * 4 + i) * C_OUT + o], acc[i]);
    }
#pragma unroll
    for (int i = 0; i < 4; ++i)
      out[((size_t)(th * 4 + i) * N_NODES + j) * C_OUT + o] = fmaxf(acc[i] + b, 0.f);
  }
}

// ---------------- host ----------------
extern "C" void kernel_launch(void* const* d_in, const int* in_sizes, int n_in,
                              void* d_out, int out_size, void* d_ws, size_t ws_size,
                              hipStream_t stream) {
  (void)in_sizes; (void)n_in; (void)out_size; (void)ws_size;
  const float* x       = (const float*)d_in[0];
  const int*   ei      = (const int*)d_in[1];
  const float* ewt     = (const float*)d_in[2];
  const float* tconv_w = (const float*)d_in[3];
  const float* tconv_b = (const float*)d_in[4];
  const float* ln_g    = (const float*)d_in[5];
  const float* ln_b    = (const float*)d_in[6];
  const float* res_w   = (const float*)d_in[7];
  const float* res_b   = (const float*)d_in[8];
  const float* gcn_w   = (const float*)d_in[9];
  const float* gcn_b   = (const float*)d_in[10];
  float* out = (float*)d_out;

  // xcmb lives in d_out (dead scratch until k_agg overwrites it): [t][n][128] fp32 = out_size exactly
  float* xcmb = out;

  // workspace carve (~85 MB)
  float* wsf   = (float*)d_ws;
  float* xt    = wsf;                                      // N*T*128 fp32 (81.92 MB, 16B-aligned)
  unsigned int* Bf = (unsigned int*)(xt + (size_t)N_NODES * T_STEPS * C_OUT);  // 24576 u32
  float* ewv   = (float*)(Bf + 24576);                     // E
  float* normv = ewv + E_EDGES;                            // E
  float* deg   = normv + E_EDGES;                          // N
  float* dinv  = deg + N_NODES;                            // N
  float* pm    = dinv + N_NODES;                           // 256
  float* ps    = pm + 256;                                 // 256
  int*   cnt    = (int*)(ps + 256);                        // N
  int*   off    = cnt + N_NODES;                           // N+1
  int*   cursor = off + N_NODES + 1;                       // N
  int*   eidx   = cursor + N_NODES;                        // E

  const int nblk = (N_NODES + 255) / 256;                  // 79
  const int eblk = E_EDGES / 256;                          // 625 exact

  k_wprep<<<96, 256, 0, stream>>>(tconv_w, res_w, gcn_w, Bf);
  k_init<<<nblk, 256, 0, stream>>>(deg, cnt);
  k_pmax<<<256, 256, 0, stream>>>(ewt, pm);
  k_sumexp<<<256, 256, 0, stream>>>(ewt, pm, ps);
  k_edge<<<eblk, 256, 0, stream>>>(ewt, ei, pm, ps, ewv, deg, cnt);
  k_dinv<<<nblk, 256, 0, stream>>>(deg, dinv);
  k_scan<<<1, 256, 0, stream>>>(cnt, off, cursor);
  k_norm_scatter<<<eblk, 256, 0, stream>>>(ei, ewv, dinv, cursor, normv, eidx);

  k_node_mfma<<<dim3(157, T_STEPS), 256, 0, stream>>>(x, tconv_b, ln_g, ln_b, res_b, Bf, xcmb);
  k_xt_mfma<<<1250, 256, 0, stream>>>(xcmb, Bf, xt);
  k_agg<<<N_NODES / NPB_AGG, 256, 0, stream>>>(xt, ei, normv, off, eidx, dinv, gcn_b, out);
}

// Round 4
// 246.477 us; speedup vs baseline: 4.8835x; 1.2015x over previous
//
#include <hip/hip_runtime.h>
#include <math.h>

// EnhancedSTGCNLayer: x[T,N,64] -> tconv(k=3)+LN+ReLU+res -> GCNConv(softmax ew, self loops) -> [T,N,128]
#define N_NODES 20000
#define E_EDGES 160000
#define T_STEPS 8
#define C_IN    64
#define C_OUT   128

typedef __bf16 bf16x8 __attribute__((ext_vector_type(8)));
typedef float  f32x4  __attribute__((ext_vector_type(4)));
#define MFMA16(a, b, c) __builtin_amdgcn_mfma_f32_16x16x32_bf16((a), (b), (c), 0, 0, 0)

__device__ __forceinline__ unsigned short f2u(float f) {
  __bf16 b = (__bf16)f;                       // RNE fp32->bf16
  return __builtin_bit_cast(unsigned short, b);
}
__device__ __forceinline__ unsigned int pack2(float lo, float hi) {
  return (unsigned int)f2u(lo) | ((unsigned int)f2u(hi) << 16);
}
__device__ __forceinline__ float ulo(unsigned int u) { return __builtin_bit_cast(float, u << 16); }
__device__ __forceinline__ float uhi(unsigned int u) { return __builtin_bit_cast(float, u & 0xffff0000u); }

// ---------------- reduction helpers ----------------
__device__ __forceinline__ float wredSum(float v) {
#pragma unroll
  for (int d = 32; d > 0; d >>= 1) v += __shfl_xor(v, d, 64);
  return v;
}
__device__ __forceinline__ float wredMax(float v) {
#pragma unroll
  for (int d = 32; d > 0; d >>= 1) v = fmaxf(v, __shfl_xor(v, d, 64));
  return v;
}
__device__ __forceinline__ float bredSum(float v, float* sm4) {
  __syncthreads();
  v = wredSum(v);
  const int lane = threadIdx.x & 63, wid = threadIdx.x >> 6;
  if (lane == 0) sm4[wid] = v;
  __syncthreads();
  return sm4[0] + sm4[1] + sm4[2] + sm4[3];
}
__device__ __forceinline__ float bredMax(float v, float* sm4) {
  __syncthreads();
  v = wredMax(v);
  const int lane = threadIdx.x & 63, wid = threadIdx.x >> 6;
  if (lane == 0) sm4[wid] = v;
  __syncthreads();
  return fmaxf(fmaxf(sm4[0], sm4[1]), fmaxf(sm4[2], sm4[3]));
}

// ---------------- x -> bf16 pre-convert (identical rounding to MFMA staging) ----------------
__global__ __launch_bounds__(256) void k_xcvt(const float* __restrict__ x, unsigned short* __restrict__ xb) {
  const size_t M = (size_t)T_STEPS * N_NODES * C_IN / 4;  // 2,560,000 float4 chunks
  const size_t step = (size_t)gridDim.x * 256;
  for (size_t i = (size_t)blockIdx.x * 256 + threadIdx.x; i < M; i += step) {
    const float4 v = ((const float4*)x)[i];
    uint2 pk; pk.x = pack2(v.x, v.y); pk.y = pack2(v.z, v.w);
    ((uint2*)xb)[i] = pk;
  }
}

// ---------------- edge-weight softmax stats ----------------
__global__ __launch_bounds__(256) void k_pmax(const float* __restrict__ w, float* __restrict__ pm) {
  __shared__ float sm4[4];
  float m = -3.4e38f;
  for (int i = blockIdx.x * 256 + threadIdx.x; i < E_EDGES; i += 256 * 256) m = fmaxf(m, w[i]);
  m = bredMax(m, sm4);
  if (threadIdx.x == 0) pm[blockIdx.x] = m;
}

__global__ __launch_bounds__(256) void k_sumexp(const float* __restrict__ w, const float* __restrict__ pm,
                                                float* __restrict__ ps) {
  __shared__ float sm4[4];
  const float mx = bredMax(pm[threadIdx.x], sm4);
  float s = 0.f;
  for (int i = blockIdx.x * 256 + threadIdx.x; i < E_EDGES; i += 256 * 256) s += expf(w[i] - mx);
  s = bredSum(s, sm4);
  if (threadIdx.x == 0) ps[blockIdx.x] = s;
}

__global__ __launch_bounds__(256) void k_init(float* __restrict__ deg, int* __restrict__ cnt) {
  const int i = blockIdx.x * 256 + threadIdx.x;
  if (i < N_NODES) { deg[i] = 1.0f; cnt[i] = 0; }
}

__global__ __launch_bounds__(256) void k_edge(const float* __restrict__ w, const int* __restrict__ ei,
                                              const float* __restrict__ pm, const float* __restrict__ ps,
                                              float* __restrict__ ewv, float* __restrict__ deg,
                                              int* __restrict__ cnt) {
  __shared__ float sm4[4];
  const float mx  = bredMax(pm[threadIdx.x], sm4);
  const float sum = bredSum(ps[threadIdx.x], sm4);
  const int e = blockIdx.x * 256 + threadIdx.x;  // grid = E/256 exact
  const float v = expf(w[e] - mx) / sum;
  ewv[e] = v;
  const int c = ei[E_EDGES + e];
  atomicAdd(&deg[c], v);
  atomicAdd(&cnt[c], 1);
}

__global__ __launch_bounds__(256) void k_dinv(const float* __restrict__ deg, float* __restrict__ dinv) {
  const int i = blockIdx.x * 256 + threadIdx.x;
  if (i < N_NODES) dinv[i] = rsqrtf(deg[i]);
}

// single-block exclusive scan of cnt[N] -> off[N+1]; cursor = off copy
__global__ __launch_bounds__(256) void k_scan(const int* __restrict__ cnt, int* __restrict__ off,
                                              int* __restrict__ cursor) {
  __shared__ int wpart[4];
  __shared__ int s_carry;
  const int tid = threadIdx.x, lane = tid & 63, wid = tid >> 6;
  if (tid == 0) s_carry = 0;
  __syncthreads();
  for (int base = 0; base < N_NODES; base += 256) {
    const int i = base + tid;
    const int v = (i < N_NODES) ? cnt[i] : 0;
    int s = v;
#pragma unroll
    for (int d = 1; d < 64; d <<= 1) { const int u = __shfl_up(s, d, 64); if (lane >= d) s += u; }
    if (lane == 63) wpart[wid] = s;
    const int carry = s_carry;
    __syncthreads();
    int add = 0;
#pragma unroll
    for (int wv = 0; wv < 4; ++wv) if (wv < wid) add += wpart[wv];
    if (i < N_NODES) { const int excl = carry + add + (s - v); off[i] = excl; cursor[i] = excl; }
    __syncthreads();
    if (tid == 255) s_carry = carry + add + s;
    __syncthreads();
  }
  if (threadIdx.x == 0) off[N_NODES] = E_EDGES;
}

__global__ __launch_bounds__(256) void k_norm_scatter(const int* __restrict__ ei, const float* __restrict__ ewv,
                                                      const float* __restrict__ dinv, int* __restrict__ cursor,
                                                      float* __restrict__ normv, int* __restrict__ eidx) {
  const int e = blockIdx.x * 256 + threadIdx.x;
  const int r = ei[e], c = ei[E_EDGES + e];
  normv[e] = dinv[r] * ewv[e] * dinv[c];
  const int pos = atomicAdd(&cursor[c], 1);
  eidx[pos] = e;
}

// ---------------- weight prep: pack B matrices into MFMA fragment order (bf16 pairs) ----------------
__global__ __launch_bounds__(256) void k_wprep(const float* __restrict__ tconv_w, const float* __restrict__ res_w,
                                               const float* __restrict__ gcn_w, unsigned int* __restrict__ Bf) {
  const int gid = blockIdx.x * 256 + threadIdx.x;  // 96 blocks * 256 = 24576 exact
  float v0, v1;
  if (gid < 12288) {
    const int reg = gid & 3, l = (gid >> 2) & 63, ct = (gid >> 8) & 7, ks = gid >> 11;
    const int o = ct * 16 + (l & 15);
    const int k0 = ks * 32 + ((l >> 4) & 3) * 8 + reg * 2;
    const int c0 = k0 & 63, tap0 = k0 >> 6;
    const int c1 = (k0 + 1) & 63, tap1 = (k0 + 1) >> 6;
    v0 = tconv_w[o * 192 + c0 * 3 + tap0];
    v1 = tconv_w[o * 192 + c1 * 3 + tap1];
  } else if (gid < 16384) {
    const int g = gid - 12288;
    const int reg = g & 3, l = (g >> 2) & 63, ct = (g >> 8) & 7, ks = g >> 11;
    const int o = ct * 16 + (l & 15);
    const int k0 = ks * 32 + ((l >> 4) & 3) * 8 + reg * 2;
    v0 = res_w[o * 64 + k0];
    v1 = res_w[o * 64 + k0 + 1];
  } else {
    const int g = gid - 16384;
    const int reg = g & 3, l = (g >> 2) & 63, ct = (g >> 8) & 7, ks = g >> 11;
    const int o = ct * 16 + (l & 15);
    const int k0 = ks * 32 + ((l >> 4) & 3) * 8 + reg * 2;
    v0 = gcn_w[o * 128 + k0];
    v1 = gcn_w[o * 128 + k0 + 1];
  }
  Bf[gid] = pack2(v0, v1);
}

// ---------------- node transform via MFMA: tconv + LN + ReLU + res -> xcmb bf16 [t][n][o] ----------------
#define AS_STRIDE 200  // bf16 units; 400B row stride (16B-aligned), conflict-free b128 frag reads
__global__ __launch_bounds__(256) void k_node_mfma(const unsigned short* __restrict__ xb,
                                                   const float* __restrict__ tconv_b,
                                                   const float* __restrict__ ln_g, const float* __restrict__ ln_b,
                                                   const float* __restrict__ res_b,
                                                   const unsigned int* __restrict__ Bf,
                                                   unsigned short* __restrict__ xcmb) {
  const int tid = threadIdx.x, lane = tid & 63, w = tid >> 6;
  const int l15 = lane & 15, lg = lane >> 4;
  const int t = blockIdx.y;
  const int n0 = blockIdx.x * 128;

  __shared__ unsigned short As[128 * AS_STRIDE];
  __shared__ float psum[4][64], psq[4][64], smu[64], srs[64];

  // ---- stage A-tile from bf16 x: [row][tap*64+c], zero-pad at t edges ----
#pragma unroll
  for (int tap = 0; tap < 3; ++tap) {
    const int tq = t + tap - 1;
    const int valid = (tq >= 0 && tq < T_STEPS);
#pragma unroll
    for (int p = 0; p < 4; ++p) {
      const int chunk = p * 256 + tid;          // 1024 = 128 rows * 8 chunks of 8 bf16
      const int row = chunk >> 3, c8 = chunk & 7;
      int n = n0 + row; n = (n < N_NODES) ? n : (N_NODES - 1);
      uint4 v = make_uint4(0u, 0u, 0u, 0u);
      if (valid) v = *(const uint4*)(xb + ((size_t)tq * N_NODES + n) * C_IN + c8 * 8);
      *(uint4*)&As[row * AS_STRIDE + tap * 64 + c8 * 8] = v;
    }
  }

  // ---- B fragments (resident in VGPRs) ----
  const uint4* Bf4 = (const uint4*)Bf;
  uint4 Bc[2][6], Br[2][2];
#pragma unroll
  for (int ct = 0; ct < 2; ++ct) {
    const int ctg = w * 2 + ct;
#pragma unroll
    for (int ks = 0; ks < 6; ++ks) Bc[ct][ks] = Bf4[(ks * 8 + ctg) * 64 + lane];
#pragma unroll
    for (int ks = 0; ks < 2; ++ks) Br[ct][ks] = Bf4[3072 + (ks * 8 + ctg) * 64 + lane];
  }
  float cb[2], rb[2], gv[2], bv[2];
#pragma unroll
  for (int ct = 0; ct < 2; ++ct) {
    const int col = w * 32 + ct * 16 + l15;
    cb[ct] = tconv_b[col]; rb[ct] = res_b[col]; gv[ct] = ln_g[col]; bv[ct] = ln_b[col];
  }
  __syncthreads();

#pragma unroll
  for (int h = 0; h < 2; ++h) {
    f32x4 accC[4][2], accR[4][2];
#pragma unroll
    for (int rt = 0; rt < 4; ++rt)
#pragma unroll
      for (int ct = 0; ct < 2; ++ct) { accC[rt][ct] = (f32x4)0.f; accR[rt][ct] = (f32x4)0.f; }

#pragma unroll
    for (int ks = 0; ks < 6; ++ks) {
      bf16x8 af[4];
#pragma unroll
      for (int rt = 0; rt < 4; ++rt)
        af[rt] = *(const bf16x8*)&As[(h * 64 + rt * 16 + l15) * AS_STRIDE + ks * 32 + lg * 8];
#pragma unroll
      for (int rt = 0; rt < 4; ++rt)
#pragma unroll
        for (int ct = 0; ct < 2; ++ct)
          accC[rt][ct] = MFMA16(af[rt], __builtin_bit_cast(bf16x8, Bc[ct][ks]), accC[rt][ct]);
      if (ks == 2 || ks == 3) {  // middle tap (k 64..127) drives the 1x1 residual conv
#pragma unroll
        for (int rt = 0; rt < 4; ++rt)
#pragma unroll
          for (int ct = 0; ct < 2; ++ct)
            accR[rt][ct] = MFMA16(af[rt], __builtin_bit_cast(bf16x8, Br[ct][ks - 2]), accR[rt][ct]);
      }
    }

    // ---- LayerNorm stats (C-layout: row=(lane>>4)*4+j, col=16*ct+l15) ----
#pragma unroll
    for (int rt = 0; rt < 4; ++rt) {
      float s[4], s2[4];
#pragma unroll
      for (int j = 0; j < 4; ++j) {
        const float h0 = accC[rt][0][j] + cb[0];
        const float h1 = accC[rt][1][j] + cb[1];
        accC[rt][0][j] = h0; accC[rt][1][j] = h1;
        s[j] = h0 + h1; s2[j] = h0 * h0 + h1 * h1;
      }
#pragma unroll
      for (int d = 1; d < 16; d <<= 1)
#pragma unroll
        for (int j = 0; j < 4; ++j) { s[j] += __shfl_xor(s[j], d, 64); s2[j] += __shfl_xor(s2[j], d, 64); }
      if (l15 == 0)
#pragma unroll
        for (int j = 0; j < 4; ++j) {
          psum[w][rt * 16 + lg * 4 + j] = s[j];
          psq[w][rt * 16 + lg * 4 + j] = s2[j];
        }
    }
    __syncthreads();
    if (tid < 64) {
      const float S  = psum[0][tid] + psum[1][tid] + psum[2][tid] + psum[3][tid];
      const float S2 = psq[0][tid] + psq[1][tid] + psq[2][tid] + psq[3][tid];
      const float mu = S * (1.f / 128.f);
      const float var = S2 * (1.f / 128.f) - mu * mu;
      smu[tid] = mu; srs[tid] = rsqrtf(var + 1e-5f);
    }
    __syncthreads();

    // ---- apply LN + ReLU + residual, store bf16 ----
#pragma unroll
    for (int rt = 0; rt < 4; ++rt)
#pragma unroll
      for (int j = 0; j < 4; ++j) {
        const int row64 = rt * 16 + lg * 4 + j;
        const float mu = smu[row64], rs = srs[row64];
        const int n = n0 + h * 64 + row64;
        if (n < N_NODES) {
#pragma unroll
          for (int ct = 0; ct < 2; ++ct) {
            float xc = (accC[rt][ct][j] - mu) * rs * gv[ct] + bv[ct];
            xc = fmaxf(xc, 0.f) + accR[rt][ct][j] + rb[ct];
            xcmb[((size_t)t * N_NODES + n) * C_OUT + w * 32 + ct * 16 + l15] = f2u(xc);
          }
        }
      }
    __syncthreads();  // protect psum/smu reuse for next half
  }
}

// ---------------- GCN linear via MFMA: xt[n][o][t] bf16 = xcmb rows @ gcn_w^T ----------------
// block = 16 nodes x 8 t = 128 rows; row_local = nn*8 + t so stores pack 4 t's per uint2
#define AS2_STRIDE 136
__global__ __launch_bounds__(256) void k_xt_mfma(const unsigned short* __restrict__ xcmb,
                                                 const unsigned int* __restrict__ Bf,
                                                 unsigned short* __restrict__ xt) {
  const int tid = threadIdx.x, lane = tid & 63, w = tid >> 6;
  const int l15 = lane & 15, lg = lane >> 4;
  const int n0 = blockIdx.x * 16;               // 1250 blocks exact

  __shared__ unsigned short As[128 * AS2_STRIDE];
#pragma unroll
  for (int p = 0; p < 8; ++p) {
    const int chunk = p * 256 + tid;            // 2048 = 128 rows * 16 chunks of 8 bf16
    const int rl = chunk >> 4, c8 = chunk & 15;
    const int nn = rl >> 3, t = rl & 7;
    const uint4 v = *(const uint4*)(xcmb + ((size_t)t * N_NODES + n0 + nn) * C_OUT + c8 * 8);
    *(uint4*)&As[rl * AS2_STRIDE + c8 * 8] = v;
  }
  const uint4* Bf4 = (const uint4*)Bf;
  uint4 Bg[2][4];
#pragma unroll
  for (int ct = 0; ct < 2; ++ct)
#pragma unroll
    for (int ks = 0; ks < 4; ++ks) Bg[ct][ks] = Bf4[4096 + (ks * 8 + (w * 2 + ct)) * 64 + lane];
  __syncthreads();

  f32x4 acc[8][2];
#pragma unroll
  for (int rt = 0; rt < 8; ++rt)
#pragma unroll
    for (int ct = 0; ct < 2; ++ct) acc[rt][ct] = (f32x4)0.f;

#pragma unroll
  for (int ks = 0; ks < 4; ++ks) {
    bf16x8 af[8];
#pragma unroll
    for (int rt = 0; rt < 8; ++rt)
      af[rt] = *(const bf16x8*)&As[(rt * 16 + l15) * AS2_STRIDE + ks * 32 + lg * 8];
#pragma unroll
    for (int rt = 0; rt < 8; ++rt)
#pragma unroll
      for (int ct = 0; ct < 2; ++ct)
        acc[rt][ct] = MFMA16(af[rt], __builtin_bit_cast(bf16x8, Bg[ct][ks]), acc[rt][ct]);
  }

  // store: row128 = rt*16+lg*4+j -> nn = rt*2+(lg>>1), t = (lg&1)*4 + j
  const int t0 = (lg & 1) * 4;
#pragma unroll
  for (int rt = 0; rt < 8; ++rt) {
    const int nn = rt * 2 + (lg >> 1);
    const size_t n = (size_t)(n0 + nn);
#pragma unroll
    for (int ct = 0; ct < 2; ++ct) {
      const int col = w * 32 + ct * 16 + l15;
      uint2 pk;
      pk.x = pack2(acc[rt][ct][0], acc[rt][ct][1]);
      pk.y = pack2(acc[rt][ct][2], acc[rt][ct][3]);
      *(uint2*)(xt + (n * C_OUT + col) * T_STEPS + t0) = pk;
    }
  }
}

// ---------------- CSR aggregation + bias + ReLU -> out[T,N,128] ----------------
// xt layout [n][o][t] bf16: per edge each thread loads ONE uint2 (4 t-values)
#define NPB_AGG 4
__global__ __launch_bounds__(256) void k_agg(const unsigned short* __restrict__ xt, const int* __restrict__ ei,
                                             const float* __restrict__ normv, const int* __restrict__ off,
                                             const int* __restrict__ eidx, const float* __restrict__ dinv,
                                             const float* __restrict__ gcn_b, float* __restrict__ out) {
  const int tid = threadIdx.x, o = tid & 127, th = tid >> 7;
  const float b = gcn_b[o];
  for (int jj = 0; jj < NPB_AGG; ++jj) {
    const int j = blockIdx.x * NPB_AGG + jj;
    const int s = off[j], e = off[j + 1];
    const float d2 = dinv[j] * dinv[j];
    float acc[4];
    {
      const uint2 pk = *(const uint2*)(xt + ((size_t)j * C_OUT + o) * T_STEPS + th * 4);
      acc[0] = d2 * ulo(pk.x); acc[1] = d2 * uhi(pk.x);
      acc[2] = d2 * ulo(pk.y); acc[3] = d2 * uhi(pk.y);
    }
    for (int k = s; k < e; ++k) {
      const int eid = eidx[k];
      const int r = ei[eid];
      const float nm = normv[eid];
      const uint2 pk = *(const uint2*)(xt + ((size_t)r * C_OUT + o) * T_STEPS + th * 4);
      acc[0] = fmaf(nm, ulo(pk.x), acc[0]);
      acc[1] = fmaf(nm, uhi(pk.x), acc[1]);
      acc[2] = fmaf(nm, ulo(pk.y), acc[2]);
      acc[3] = fmaf(nm, uhi(pk.y), acc[3]);
    }
#pragma unroll
    for (int i = 0; i < 4; ++i)
      out[((size_t)(th * 4 + i) * N_NODES + j) * C_OUT + o] = fmaxf(acc[i] + b, 0.f);
  }
}

// ---------------- host ----------------
extern "C" void kernel_launch(void* const* d_in, const int* in_sizes, int n_in,
                              void* d_out, int out_size, void* d_ws, size_t ws_size,
                              hipStream_t stream) {
  (void)in_sizes; (void)n_in; (void)out_size; (void)ws_size;
  const float* x       = (const float*)d_in[0];
  const int*   ei      = (const int*)d_in[1];
  const float* ewt     = (const float*)d_in[2];
  const float* tconv_w = (const float*)d_in[3];
  const float* tconv_b = (const float*)d_in[4];
  const float* ln_g    = (const float*)d_in[5];
  const float* ln_b    = (const float*)d_in[6];
  const float* res_w   = (const float*)d_in[7];
  const float* res_b   = (const float*)d_in[8];
  const float* gcn_w   = (const float*)d_in[9];
  const float* gcn_b   = (const float*)d_in[10];
  float* out = (float*)d_out;

  // xcmb (bf16, 41 MB) lives in d_out's first half — dead scratch until k_agg rewrites out
  unsigned short* xcmb = (unsigned short*)d_out;

  // workspace carve (~64 MB)
  unsigned short* xt = (unsigned short*)d_ws;              // N*128*8 bf16 = 40.96 MB
  unsigned short* xb = xt + (size_t)N_NODES * C_OUT * T_STEPS;  // T*N*64 bf16 = 20.48 MB
  unsigned int* Bf = (unsigned int*)(xb + (size_t)T_STEPS * N_NODES * C_IN);  // 24576 u32
  float* ewv   = (float*)(Bf + 24576);                     // E
  float* normv = ewv + E_EDGES;                            // E
  float* deg   = normv + E_EDGES;                          // N
  float* dinv  = deg + N_NODES;                            // N
  float* pm    = dinv + N_NODES;                           // 256
  float* ps    = pm + 256;                                 // 256
  int*   cnt    = (int*)(ps + 256);                        // N
  int*   off    = cnt + N_NODES;                           // N+1
  int*   cursor = off + N_NODES + 1;                       // N
  int*   eidx   = cursor + N_NODES;                        // E

  const int nblk = (N_NODES + 255) / 256;                  // 79
  const int eblk = E_EDGES / 256;                          // 625 exact

  k_wprep<<<96, 256, 0, stream>>>(tconv_w, res_w, gcn_w, Bf);
  k_xcvt<<<2500, 256, 0, stream>>>(x, xb);
  k_init<<<nblk, 256, 0, stream>>>(deg, cnt);
  k_pmax<<<256, 256, 0, stream>>>(ewt, pm);
  k_sumexp<<<256, 256, 0, stream>>>(ewt, pm, ps);
  k_edge<<<eblk, 256, 0, stream>>>(ewt, ei, pm, ps, ewv, deg, cnt);
  k_dinv<<<nblk, 256, 0, stream>>>(deg, dinv);
  k_scan<<<1, 256, 0, stream>>>(cnt, off, cursor);
  k_norm_scatter<<<eblk, 256, 0, stream>>>(ei, ewv, dinv, cursor, normv, eidx);

  k_node_mfma<<<dim3(157, T_STEPS), 256, 0, stream>>>(xb, tconv_b, ln_g, ln_b, res_b, Bf, xcmb);
  k_xt_mfma<<<1250, 256, 0, stream>>>(xcmb, Bf, xt);
  k_agg<<<N_NODES / NPB_AGG, 256, 0, stream>>>(xt, ei, normv, off, eidx, dinv, gcn_b, out);
}

// Round 5
// 172.542 us; speedup vs baseline: 6.9761x; 1.4285x over previous
//
#include <hip/hip_runtime.h>
#include <math.h>

// EnhancedSTGCNLayer: x[T,N,64] -> tconv(k=3)+LN+ReLU+res -> GCNConv(softmax ew, self loops) -> [T,N,128]
#define N_NODES 20000
#define E_EDGES 160000
#define T_STEPS 8
#define C_IN    64
#define C_OUT   128

typedef __bf16 bf16x8 __attribute__((ext_vector_type(8)));
typedef float  f32x4  __attribute__((ext_vector_type(4)));
#define MFMA16(a, b, c) __builtin_amdgcn_mfma_f32_16x16x32_bf16((a), (b), (c), 0, 0, 0)

__device__ __forceinline__ unsigned short f2u(float f) {
  __bf16 b = (__bf16)f;                       // RNE fp32->bf16
  return __builtin_bit_cast(unsigned short, b);
}
__device__ __forceinline__ unsigned int pack2(float lo, float hi) {
  return (unsigned int)f2u(lo) | ((unsigned int)f2u(hi) << 16);
}
__device__ __forceinline__ float ulo(unsigned int u) { return __builtin_bit_cast(float, u << 16); }
__device__ __forceinline__ float uhi(unsigned int u) { return __builtin_bit_cast(float, u & 0xffff0000u); }

// ---------------- reduction helpers ----------------
__device__ __forceinline__ float wredSum(float v) {
#pragma unroll
  for (int d = 32; d > 0; d >>= 1) v += __shfl_xor(v, d, 64);
  return v;
}
__device__ __forceinline__ float wredMax(float v) {
#pragma unroll
  for (int d = 32; d > 0; d >>= 1) v = fmaxf(v, __shfl_xor(v, d, 64));
  return v;
}
__device__ __forceinline__ int wredSumI(int v) {
#pragma unroll
  for (int d = 32; d > 0; d >>= 1) v += __shfl_xor(v, d, 64);
  return v;
}
__device__ __forceinline__ float bredSum(float v, float* sm4) {
  __syncthreads();
  v = wredSum(v);
  const int lane = threadIdx.x & 63, wid = threadIdx.x >> 6;
  if (lane == 0) sm4[wid] = v;
  __syncthreads();
  return sm4[0] + sm4[1] + sm4[2] + sm4[3];
}
__device__ __forceinline__ float bredMax(float v, float* sm4) {
  __syncthreads();
  v = wredMax(v);
  const int lane = threadIdx.x & 63, wid = threadIdx.x >> 6;
  if (lane == 0) sm4[wid] = v;
  __syncthreads();
  return fmaxf(fmaxf(sm4[0], sm4[1]), fmaxf(sm4[2], sm4[3]));
}

// ---------------- edge-weight softmax stats ----------------
__global__ __launch_bounds__(256) void k_pmax(const float* __restrict__ w, float* __restrict__ pm) {
  __shared__ float sm4[4];
  float m = -3.4e38f;
  for (int i = blockIdx.x * 256 + threadIdx.x; i < E_EDGES; i += 256 * 256) m = fmaxf(m, w[i]);
  m = bredMax(m, sm4);
  if (threadIdx.x == 0) pm[blockIdx.x] = m;
}

__global__ __launch_bounds__(256) void k_sumexp(const float* __restrict__ w, const float* __restrict__ pm,
                                                float* __restrict__ ps) {
  __shared__ float sm4[4];
  const float mx = bredMax(pm[threadIdx.x], sm4);
  float s = 0.f;
  for (int i = blockIdx.x * 256 + threadIdx.x; i < E_EDGES; i += 256 * 256) s += expf(w[i] - mx);
  s = bredSum(s, sm4);
  if (threadIdx.x == 0) ps[blockIdx.x] = s;
}

__global__ __launch_bounds__(256) void k_init(float* __restrict__ deg, int* __restrict__ cnt) {
  const int i = blockIdx.x * 256 + threadIdx.x;
  if (i < N_NODES) { deg[i] = 1.0f; cnt[i] = 0; }
}

__global__ __launch_bounds__(256) void k_edge(const float* __restrict__ w, const int* __restrict__ ei,
                                              const float* __restrict__ pm, const float* __restrict__ ps,
                                              float* __restrict__ ewv, float* __restrict__ deg,
                                              int* __restrict__ cnt) {
  __shared__ float sm4[4];
  const float mx  = bredMax(pm[threadIdx.x], sm4);
  const float sum = bredSum(ps[threadIdx.x], sm4);
  const int e = blockIdx.x * 256 + threadIdx.x;  // grid = E/256 exact
  const float v = expf(w[e] - mx) / sum;
  ewv[e] = v;
  const int c = ei[E_EDGES + e];
  atomicAdd(&deg[c], v);
  atomicAdd(&cnt[c], 1);
}

// ---------------- parallel CSR scan (3 kernels) ----------------
// A: per-256-chunk count sums (fused: dinv = rsqrt(deg))
__global__ __launch_bounds__(256) void k_scanA(const int* __restrict__ cnt, const float* __restrict__ deg,
                                               float* __restrict__ dinv, int* __restrict__ csum) {
  __shared__ int sm4[4];
  const int i = blockIdx.x * 256 + threadIdx.x;
  const int v = (i < N_NODES) ? cnt[i] : 0;
  if (i < N_NODES) dinv[i] = rsqrtf(deg[i]);  // deg >= 1 (self loop)
  int s = wredSumI(v);
  const int lane = threadIdx.x & 63, wid = threadIdx.x >> 6;
  if (lane == 0) sm4[wid] = s;
  __syncthreads();
  if (threadIdx.x == 0) csum[blockIdx.x] = sm4[0] + sm4[1] + sm4[2] + sm4[3];
}

// B: exclusive scan of the 79 chunk sums (single block, Hillis-Steele over 128)
__global__ __launch_bounds__(128) void k_scanB(const int* __restrict__ csum, int* __restrict__ cbase) {
  __shared__ int buf[128];
  const int tid = threadIdx.x;
  const int nchunk = (N_NODES + 255) / 256;
  const int v = (tid < nchunk) ? csum[tid] : 0;
  buf[tid] = v;
  __syncthreads();
#pragma unroll
  for (int d = 1; d < 128; d <<= 1) {
    const int u = (tid >= d) ? buf[tid - d] : 0;
    __syncthreads();
    buf[tid] += u;
    __syncthreads();
  }
  if (tid < nchunk) cbase[tid] = buf[tid] - v;  // exclusive
}

// C: per-chunk exclusive scan + base -> off, cursor
__global__ __launch_bounds__(256) void k_scanC(const int* __restrict__ cnt, const int* __restrict__ cbase,
                                               int* __restrict__ off, int* __restrict__ cursor) {
  __shared__ int wpart[4];
  const int tid = threadIdx.x, lane = tid & 63, wid = tid >> 6;
  const int i = blockIdx.x * 256 + tid;
  const int v = (i < N_NODES) ? cnt[i] : 0;
  int s = v;  // inclusive wave scan
#pragma unroll
  for (int d = 1; d < 64; d <<= 1) { const int u = __shfl_up(s, d, 64); if (lane >= d) s += u; }
  if (lane == 63) wpart[wid] = s;
  __syncthreads();
  int add = cbase[blockIdx.x];
#pragma unroll
  for (int wv = 0; wv < 4; ++wv) if (wv < wid) add += wpart[wv];
  if (i < N_NODES) { const int excl = add + (s - v); off[i] = excl; cursor[i] = excl; }
  if (i == N_NODES - 1) off[N_NODES] = E_EDGES;
}

// per-edge: sym-norm coefficient + CSR scatter {src, norm} by destination
__global__ __launch_bounds__(256) void k_norm_scatter(const int* __restrict__ ei, const float* __restrict__ ewv,
                                                      const float* __restrict__ dinv, int* __restrict__ cursor,
                                                      uint2* __restrict__ srcnrm) {
  const int e = blockIdx.x * 256 + threadIdx.x;  // grid = E/256 exact
  const int r = ei[e], c = ei[E_EDGES + e];
  const float nm = dinv[r] * ewv[e] * dinv[c];
  const int pos = atomicAdd(&cursor[c], 1);
  srcnrm[pos] = make_uint2((unsigned int)r, __builtin_bit_cast(unsigned int, nm));
}

// ---------------- weight prep: pack B matrices into MFMA fragment order (bf16 pairs) ----------------
__global__ __launch_bounds__(256) void k_wprep(const float* __restrict__ tconv_w, const float* __restrict__ res_w,
                                               const float* __restrict__ gcn_w, unsigned int* __restrict__ Bf) {
  const int gid = blockIdx.x * 256 + threadIdx.x;  // 96 blocks * 256 = 24576 exact
  float v0, v1;
  if (gid < 12288) {
    const int reg = gid & 3, l = (gid >> 2) & 63, ct = (gid >> 8) & 7, ks = gid >> 11;
    const int o = ct * 16 + (l & 15);
    const int k0 = ks * 32 + ((l >> 4) & 3) * 8 + reg * 2;
    const int c0 = k0 & 63, tap0 = k0 >> 6;
    const int c1 = (k0 + 1) & 63, tap1 = (k0 + 1) >> 6;
    v0 = tconv_w[o * 192 + c0 * 3 + tap0];
    v1 = tconv_w[o * 192 + c1 * 3 + tap1];
  } else if (gid < 16384) {
    const int g = gid - 12288;
    const int reg = g & 3, l = (g >> 2) & 63, ct = (g >> 8) & 7, ks = g >> 11;
    const int o = ct * 16 + (l & 15);
    const int k0 = ks * 32 + ((l >> 4) & 3) * 8 + reg * 2;
    v0 = res_w[o * 64 + k0];
    v1 = res_w[o * 64 + k0 + 1];
  } else {
    const int g = gid - 16384;
    const int reg = g & 3, l = (g >> 2) & 63, ct = (g >> 8) & 7, ks = g >> 11;
    const int o = ct * 16 + (l & 15);
    const int k0 = ks * 32 + ((l >> 4) & 3) * 8 + reg * 2;
    v0 = gcn_w[o * 128 + k0];
    v1 = gcn_w[o * 128 + k0 + 1];
  }
  Bf[gid] = pack2(v0, v1);
}

// ---------------- node transform via MFMA: tconv + LN + ReLU + res -> xcmb bf16 [t][n][o] ----------------
#define AS_STRIDE 200  // bf16 units; 400B row stride (16B-aligned), conflict-free b128 frag reads
__global__ __launch_bounds__(256) void k_node_mfma(const float* __restrict__ x,
                                                   const float* __restrict__ tconv_b,
                                                   const float* __restrict__ ln_g, const float* __restrict__ ln_b,
                                                   const float* __restrict__ res_b,
                                                   const unsigned int* __restrict__ Bf,
                                                   unsigned short* __restrict__ xcmb) {
  const int tid = threadIdx.x, lane = tid & 63, w = tid >> 6;
  const int l15 = lane & 15, lg = lane >> 4;
  const int t = blockIdx.y;
  const int n0 = blockIdx.x * 128;

  __shared__ unsigned short As[128 * AS_STRIDE];
  __shared__ float psum[4][64], psq[4][64], smu[64], srs[64];

  // ---- stage A-tile from fp32 x: [row][tap*64+c] bf16, zero-pad at t edges ----
#pragma unroll
  for (int tap = 0; tap < 3; ++tap) {
    const int tq = t + tap - 1;
    const int valid = (tq >= 0 && tq < T_STEPS);
#pragma unroll
    for (int p = 0; p < 8; ++p) {
      const int chunk = p * 256 + tid;          // 2048 = 128 rows * 16 float4
      const int row = chunk >> 4, c4 = chunk & 15;
      int n = n0 + row; n = (n < N_NODES) ? n : (N_NODES - 1);
      float4 v = make_float4(0.f, 0.f, 0.f, 0.f);
      if (valid) v = *(const float4*)(x + ((size_t)tq * N_NODES + n) * C_IN + c4 * 4);
      uint2 pk;
      pk.x = pack2(v.x, v.y);
      pk.y = pack2(v.z, v.w);
      *(uint2*)&As[row * AS_STRIDE + tap * 64 + c4 * 4] = pk;
    }
  }

  // ---- B fragments (resident in VGPRs) ----
  const uint4* Bf4 = (const uint4*)Bf;
  uint4 Bc[2][6], Br[2][2];
#pragma unroll
  for (int ct = 0; ct < 2; ++ct) {
    const int ctg = w * 2 + ct;
#pragma unroll
    for (int ks = 0; ks < 6; ++ks) Bc[ct][ks] = Bf4[(ks * 8 + ctg) * 64 + lane];
#pragma unroll
    for (int ks = 0; ks < 2; ++ks) Br[ct][ks] = Bf4[3072 + (ks * 8 + ctg) * 64 + lane];
  }
  float cb[2], rb[2], gv[2], bv[2];
#pragma unroll
  for (int ct = 0; ct < 2; ++ct) {
    const int col = w * 32 + ct * 16 + l15;
    cb[ct] = tconv_b[col]; rb[ct] = res_b[col]; gv[ct] = ln_g[col]; bv[ct] = ln_b[col];
  }
  __syncthreads();

#pragma unroll
  for (int h = 0; h < 2; ++h) {
    f32x4 accC[4][2], accR[4][2];
#pragma unroll
    for (int rt = 0; rt < 4; ++rt)
#pragma unroll
      for (int ct = 0; ct < 2; ++ct) { accC[rt][ct] = (f32x4)0.f; accR[rt][ct] = (f32x4)0.f; }

#pragma unroll
    for (int ks = 0; ks < 6; ++ks) {
      bf16x8 af[4];
#pragma unroll
      for (int rt = 0; rt < 4; ++rt)
        af[rt] = *(const bf16x8*)&As[(h * 64 + rt * 16 + l15) * AS_STRIDE + ks * 32 + lg * 8];
#pragma unroll
      for (int rt = 0; rt < 4; ++rt)
#pragma unroll
        for (int ct = 0; ct < 2; ++ct)
          accC[rt][ct] = MFMA16(af[rt], __builtin_bit_cast(bf16x8, Bc[ct][ks]), accC[rt][ct]);
      if (ks == 2 || ks == 3) {  // middle tap (k 64..127) drives the 1x1 residual conv
#pragma unroll
        for (int rt = 0; rt < 4; ++rt)
#pragma unroll
          for (int ct = 0; ct < 2; ++ct)
            accR[rt][ct] = MFMA16(af[rt], __builtin_bit_cast(bf16x8, Br[ct][ks - 2]), accR[rt][ct]);
      }
    }

    // ---- LayerNorm stats (C-layout: row=(lane>>4)*4+j, col=16*ct+l15) ----
#pragma unroll
    for (int rt = 0; rt < 4; ++rt) {
      float s[4], s2[4];
#pragma unroll
      for (int j = 0; j < 4; ++j) {
        const float h0 = accC[rt][0][j] + cb[0];
        const float h1 = accC[rt][1][j] + cb[1];
        accC[rt][0][j] = h0; accC[rt][1][j] = h1;
        s[j] = h0 + h1; s2[j] = h0 * h0 + h1 * h1;
      }
#pragma unroll
      for (int d = 1; d < 16; d <<= 1)
#pragma unroll
        for (int j = 0; j < 4; ++j) { s[j] += __shfl_xor(s[j], d, 64); s2[j] += __shfl_xor(s2[j], d, 64); }
      if (l15 == 0)
#pragma unroll
        for (int j = 0; j < 4; ++j) {
          psum[w][rt * 16 + lg * 4 + j] = s[j];
          psq[w][rt * 16 + lg * 4 + j] = s2[j];
        }
    }
    __syncthreads();
    if (tid < 64) {
      const float S  = psum[0][tid] + psum[1][tid] + psum[2][tid] + psum[3][tid];
      const float S2 = psq[0][tid] + psq[1][tid] + psq[2][tid] + psq[3][tid];
      const float mu = S * (1.f / 128.f);
      const float var = S2 * (1.f / 128.f) - mu * mu;
      smu[tid] = mu; srs[tid] = rsqrtf(var + 1e-5f);
    }
    __syncthreads();

    // ---- apply LN + ReLU + residual, store bf16 ----
#pragma unroll
    for (int rt = 0; rt < 4; ++rt)
#pragma unroll
      for (int j = 0; j < 4; ++j) {
        const int row64 = rt * 16 + lg * 4 + j;
        const float mu = smu[row64], rs = srs[row64];
        const int n = n0 + h * 64 + row64;
        if (n < N_NODES) {
#pragma unroll
          for (int ct = 0; ct < 2; ++ct) {
            float xc = (accC[rt][ct][j] - mu) * rs * gv[ct] + bv[ct];
            xc = fmaxf(xc, 0.f) + accR[rt][ct][j] + rb[ct];
            xcmb[((size_t)t * N_NODES + n) * C_OUT + w * 32 + ct * 16 + l15] = f2u(xc);
          }
        }
      }
    __syncthreads();  // protect psum/smu reuse for next half
  }
}

// ---------------- GCN linear via MFMA: xt[n][o][t] bf16 + int8 quant table + per-node scale ----------------
// block = 16 nodes x 8 t = 128 rows; row_local = nn*8 + t
#define AS2_STRIDE 136
__global__ __launch_bounds__(256) void k_xt_mfma(const unsigned short* __restrict__ xcmb,
                                                 const unsigned int* __restrict__ Bf,
                                                 unsigned short* __restrict__ xt,
                                                 unsigned char* __restrict__ xq,
                                                 float* __restrict__ qsc) {
  const int tid = threadIdx.x, lane = tid & 63, w = tid >> 6;
  const int l15 = lane & 15, lg = lane >> 4;
  const int n0 = blockIdx.x * 16;               // 1250 blocks exact

  __shared__ unsigned short As[128 * AS2_STRIDE];
  __shared__ unsigned int nmax[16];
  if (tid < 16) nmax[tid] = 0u;
#pragma unroll
  for (int p = 0; p < 8; ++p) {
    const int chunk = p * 256 + tid;            // 2048 = 128 rows * 16 chunks of 8 bf16
    const int rl = chunk >> 4, c8 = chunk & 15;
    const int nn = rl >> 3, t = rl & 7;
    const uint4 v = *(const uint4*)(xcmb + ((size_t)t * N_NODES + n0 + nn) * C_OUT + c8 * 8);
    *(uint4*)&As[rl * AS2_STRIDE + c8 * 8] = v;
  }
  const uint4* Bf4 = (const uint4*)Bf;
  uint4 Bg[2][4];
#pragma unroll
  for (int ct = 0; ct < 2; ++ct)
#pragma unroll
    for (int ks = 0; ks < 4; ++ks) Bg[ct][ks] = Bf4[4096 + (ks * 8 + (w * 2 + ct)) * 64 + lane];
  __syncthreads();

  f32x4 acc[8][2];
#pragma unroll
  for (int rt = 0; rt < 8; ++rt)
#pragma unroll
    for (int ct = 0; ct < 2; ++ct) acc[rt][ct] = (f32x4)0.f;

#pragma unroll
  for (int ks = 0; ks < 4; ++ks) {
    bf16x8 af[8];
#pragma unroll
    for (int rt = 0; rt < 8; ++rt)
      af[rt] = *(const bf16x8*)&As[(rt * 16 + l15) * AS2_STRIDE + ks * 32 + lg * 8];
#pragma unroll
    for (int rt = 0; rt < 8; ++rt)
#pragma unroll
      for (int ct = 0; ct < 2; ++ct)
        acc[rt][ct] = MFMA16(af[rt], __builtin_bit_cast(bf16x8, Bg[ct][ks]), acc[rt][ct]);
  }

  // ---- per-node |max| for int8 scale ----
#pragma unroll
  for (int rt = 0; rt < 8; ++rt) {
    const int nn = rt * 2 + (lg >> 1);
    float m = 0.f;
#pragma unroll
    for (int ct = 0; ct < 2; ++ct)
#pragma unroll
      for (int j = 0; j < 4; ++j) m = fmaxf(m, fabsf(acc[rt][ct][j]));
    atomicMax(&nmax[nn], __builtin_bit_cast(unsigned int, m));  // values >= 0: uint order == float order
  }
  __syncthreads();
  if (tid < 16) qsc[n0 + tid] = __builtin_bit_cast(float, nmax[tid]) * (1.f / 127.f);

  // ---- store: row128 = rt*16+lg*4+j -> nn = rt*2+(lg>>1), t = (lg&1)*4 + j ----
  const int t0 = (lg & 1) * 4;
#pragma unroll
  for (int rt = 0; rt < 8; ++rt) {
    const int nn = rt * 2 + (lg >> 1);
    const size_t n = (size_t)(n0 + nn);
    const float mx = __builtin_bit_cast(float, nmax[nn]);
    const float inv = (mx > 0.f) ? 127.f / mx : 0.f;
#pragma unroll
    for (int ct = 0; ct < 2; ++ct) {
      const int col = w * 32 + ct * 16 + l15;
      uint2 pk;
      pk.x = pack2(acc[rt][ct][0], acc[rt][ct][1]);
      pk.y = pack2(acc[rt][ct][2], acc[rt][ct][3]);
      *(uint2*)(xt + (n * C_OUT + col) * T_STEPS + t0) = pk;
      unsigned int pk8 = 0;
#pragma unroll
      for (int j = 0; j < 4; ++j) {
        const int q = (int)rintf(acc[rt][ct][j] * inv) + 128;  // biased uint8
        pk8 |= ((unsigned int)q) << (8 * j);
      }
      *(unsigned int*)(xq + (n * C_OUT + col) * T_STEPS + t0) = pk8;
    }
  }
}

// ---------------- CSR aggregation + bias + ReLU -> out[T,N,128] ----------------
// one wave per destination; int8 gather rows (1 KB/edge), bf16 self row
__global__ __launch_bounds__(256) void k_agg(const unsigned short* __restrict__ xt,
                                             const unsigned char* __restrict__ xq,
                                             const float* __restrict__ qsc,
                                             const uint2* __restrict__ srcnrm,
                                             const int* __restrict__ off, const float* __restrict__ dinv,
                                             const float* __restrict__ gcn_b, float* __restrict__ out) {
  const int tid = threadIdx.x, lane = tid & 63, w = tid >> 6;
  const int j = blockIdx.x * 4 + w;             // grid 5000 exact
  const int s = off[j], e = off[j + 1];
  const float d2 = dinv[j] * dinv[j];

  float acc[2][8];
#pragma unroll
  for (int h = 0; h < 2; ++h) {
    const uint4 q = *(const uint4*)(xt + ((size_t)j * C_OUT + h * 64 + lane) * T_STEPS);
    acc[h][0] = d2 * ulo(q.x); acc[h][1] = d2 * uhi(q.x);
    acc[h][2] = d2 * ulo(q.y); acc[h][3] = d2 * uhi(q.y);
    acc[h][4] = d2 * ulo(q.z); acc[h][5] = d2 * uhi(q.z);
    acc[h][6] = d2 * ulo(q.w); acc[h][7] = d2 * uhi(q.w);
  }

  float summul = 0.f;
  for (int k = s; k < e; ++k) {
    const uint2 sn = srcnrm[k];                  // wave-uniform
    const int r = (int)sn.x;
    const float mul = __builtin_bit_cast(float, sn.y) * qsc[r];
    summul += mul;
    const uint2 qa = *(const uint2*)(xq + ((size_t)r * C_OUT + lane) * T_STEPS);
    const uint2 qb = *(const uint2*)(xq + ((size_t)r * C_OUT + 64 + lane) * T_STEPS);
#pragma unroll
    for (int tt = 0; tt < 4; ++tt) {
      acc[0][tt]     = fmaf((float)((qa.x >> (8 * tt)) & 0xffu), mul, acc[0][tt]);
      acc[0][4 + tt] = fmaf((float)((qa.y >> (8 * tt)) & 0xffu), mul, acc[0][4 + tt]);
      acc[1][tt]     = fmaf((float)((qb.x >> (8 * tt)) & 0xffu), mul, acc[1][tt]);
      acc[1][4 + tt] = fmaf((float)((qb.y >> (8 * tt)) & 0xffu), mul, acc[1][4 + tt]);
    }
  }

  const float corr = 128.f * summul;             // biased-uint8 correction
  const float b0 = gcn_b[lane], b1 = gcn_b[64 + lane];
#pragma unroll
  for (int h = 0; h < 2; ++h) {
    const float bo = h ? b1 : b0;
#pragma unroll
    for (int t = 0; t < 8; ++t) {
      const float v = acc[h][t] - corr + bo;
      out[((size_t)t * N_NODES + j) * C_OUT + h * 64 + lane] = fmaxf(v, 0.f);
    }
  }
}

// ---------------- host ----------------
extern "C" void kernel_launch(void* const* d_in, const int* in_sizes, int n_in,
                              void* d_out, int out_size, void* d_ws, size_t ws_size,
                              hipStream_t stream) {
  (void)in_sizes; (void)n_in; (void)out_size; (void)ws_size;
  const float* x       = (const float*)d_in[0];
  const int*   ei      = (const int*)d_in[1];
  const float* ewt     = (const float*)d_in[2];
  const float* tconv_w = (const float*)d_in[3];
  const float* tconv_b = (const float*)d_in[4];
  const float* ln_g    = (const float*)d_in[5];
  const float* ln_b    = (const float*)d_in[6];
  const float* res_w   = (const float*)d_in[7];
  const float* res_b   = (const float*)d_in[8];
  const float* gcn_w   = (const float*)d_in[9];
  const float* gcn_b   = (const float*)d_in[10];
  float* out = (float*)d_out;

  // xcmb (bf16, 41 MB) lives in d_out — dead scratch until k_agg rewrites out
  unsigned short* xcmb = (unsigned short*)d_out;

  // workspace carve (~65 MB)
  unsigned short* xt = (unsigned short*)d_ws;                       // N*128*8 bf16 = 40.96 MB
  unsigned char*  xq = (unsigned char*)(xt + (size_t)N_NODES * C_OUT * T_STEPS);  // N*128*8 u8 = 20.48 MB
  float* qsc  = (float*)(xq + (size_t)N_NODES * C_OUT * T_STEPS);   // N
  unsigned int* Bf = (unsigned int*)(qsc + N_NODES);                // 24576 u32
  float* ewv   = (float*)(Bf + 24576);                              // E
  float* deg   = ewv + E_EDGES;                                     // N
  float* dinv  = deg + N_NODES;                                     // N
  float* pm    = dinv + N_NODES;                                    // 256
  float* ps    = pm + 256;                                          // 256
  int*   cnt    = (int*)(ps + 256);                                 // N
  int*   off    = cnt + N_NODES;                                    // N+1
  int*   cursor = off + N_NODES + 1;                                // N
  int*   csum   = cursor + N_NODES;                                 // 128
  int*   cbase  = csum + 128;                                       // 128
  uint2* srcnrm = (uint2*)(((size_t)(cbase + 128) + 15) & ~(size_t)15);  // E * 8B

  const int nblk = (N_NODES + 255) / 256;                           // 79
  const int eblk = E_EDGES / 256;                                   // 625 exact

  k_wprep<<<96, 256, 0, stream>>>(tconv_w, res_w, gcn_w, Bf);
  k_init<<<nblk, 256, 0, stream>>>(deg, cnt);
  k_pmax<<<256, 256, 0, stream>>>(ewt, pm);
  k_sumexp<<<256, 256, 0, stream>>>(ewt, pm, ps);
  k_edge<<<eblk, 256, 0, stream>>>(ewt, ei, pm, ps, ewv, deg, cnt);
  k_scanA<<<nblk, 256, 0, stream>>>(cnt, deg, dinv, csum);
  k_scanB<<<1, 128, 0, stream>>>(csum, cbase);
  k_scanC<<<nblk, 256, 0, stream>>>(cnt, cbase, off, cursor);
  k_norm_scatter<<<eblk, 256, 0, stream>>>(ei, ewv, dinv, cursor, srcnrm);

  k_node_mfma<<<dim3(157, T_STEPS), 256, 0, stream>>>(x, tconv_b, ln_g, ln_b, res_b, Bf, xcmb);
  k_xt_mfma<<<1250, 256, 0, stream>>>(xcmb, Bf, xt, xq, qsc);
  k_agg<<<N_NODES / 4, 256, 0, stream>>>(xt, xq, qsc, srcnrm, off, dinv, gcn_b, out);
}

// Round 7
// 146.440 us; speedup vs baseline: 8.2195x; 1.1782x over previous
//
#include <hip/hip_runtime.h>
#include <math.h>

// EnhancedSTGCNLayer: x[T,N,64] -> tconv(k=3)+LN+ReLU+res -> GCNConv(softmax ew, self loops) -> [T,N,128]
#define N_NODES 20000
#define E_EDGES 160000
#define T_STEPS 8
#define C_IN    64
#define C_OUT   128

typedef __bf16 bf16x8 __attribute__((ext_vector_type(8)));
typedef float  f32x4  __attribute__((ext_vector_type(4)));
#define MFMA16(a, b, c) __builtin_amdgcn_mfma_f32_16x16x32_bf16((a), (b), (c), 0, 0, 0)

__device__ __forceinline__ unsigned short f2u(float f) {
  __bf16 b = (__bf16)f;                       // RNE fp32->bf16
  return __builtin_bit_cast(unsigned short, b);
}
__device__ __forceinline__ unsigned int pack2(float lo, float hi) {
  return (unsigned int)f2u(lo) | ((unsigned int)f2u(hi) << 16);
}
__device__ __forceinline__ float ulo(unsigned int u) { return __builtin_bit_cast(float, u << 16); }
__device__ __forceinline__ float uhi(unsigned int u) { return __builtin_bit_cast(float, u & 0xffff0000u); }

// ---------------- reduction helpers ----------------
__device__ __forceinline__ float wredSum(float v) {
#pragma unroll
  for (int d = 32; d > 0; d >>= 1) v += __shfl_xor(v, d, 64);
  return v;
}
__device__ __forceinline__ float wredMax(float v) {
#pragma unroll
  for (int d = 32; d > 0; d >>= 1) v = fmaxf(v, __shfl_xor(v, d, 64));
  return v;
}
__device__ __forceinline__ int wredSumI(int v) {
#pragma unroll
  for (int d = 32; d > 0; d >>= 1) v += __shfl_xor(v, d, 64);
  return v;
}
__device__ __forceinline__ float bredSum(float v, float* sm4) {
  __syncthreads();
  v = wredSum(v);
  const int lane = threadIdx.x & 63, wid = threadIdx.x >> 6;
  if (lane == 0) sm4[wid] = v;
  __syncthreads();
  return sm4[0] + sm4[1] + sm4[2] + sm4[3];
}
__device__ __forceinline__ float bredMax(float v, float* sm4) {
  __syncthreads();
  v = wredMax(v);
  const int lane = threadIdx.x & 63, wid = threadIdx.x >> 6;
  if (lane == 0) sm4[wid] = v;
  __syncthreads();
  return fmaxf(fmaxf(sm4[0], sm4[1]), fmaxf(sm4[2], sm4[3]));
}

// ---------------- edge-weight softmax stats ----------------
__global__ __launch_bounds__(256) void k_pmax(const float* __restrict__ w, float* __restrict__ pm) {
  __shared__ float sm4[4];
  float m = -3.4e38f;
  for (int i = blockIdx.x * 256 + threadIdx.x; i < E_EDGES; i += 256 * 256) m = fmaxf(m, w[i]);
  m = bredMax(m, sm4);
  if (threadIdx.x == 0) pm[blockIdx.x] = m;
}

__global__ __launch_bounds__(256) void k_sumexp(const float* __restrict__ w, const float* __restrict__ pm,
                                                float* __restrict__ ps) {
  __shared__ float sm4[4];
  const float mx = bredMax(pm[threadIdx.x], sm4);
  float s = 0.f;
  for (int i = blockIdx.x * 256 + threadIdx.x; i < E_EDGES; i += 256 * 256) s += expf(w[i] - mx);
  s = bredSum(s, sm4);
  if (threadIdx.x == 0) ps[blockIdx.x] = s;
}

__global__ __launch_bounds__(256) void k_edge(const float* __restrict__ w, const int* __restrict__ ei,
                                              const float* __restrict__ pm, const float* __restrict__ ps,
                                              float* __restrict__ ewv, float* __restrict__ deg,
                                              int* __restrict__ cnt) {
  __shared__ float sm4[4];
  const float mx  = bredMax(pm[threadIdx.x], sm4);
  const float sum = bredSum(ps[threadIdx.x], sm4);
  const int e = blockIdx.x * 256 + threadIdx.x;  // grid = E/256 exact
  const float v = expf(w[e] - mx) / sum;
  ewv[e] = v;
  const int c = ei[E_EDGES + e];
  atomicAdd(&deg[c], v);
  atomicAdd(&cnt[c], 1);
}

// ---------------- parallel CSR scan (3 kernels) ----------------
__global__ __launch_bounds__(256) void k_scanA(const int* __restrict__ cnt, const float* __restrict__ deg,
                                               float* __restrict__ dinv, int* __restrict__ csum) {
  __shared__ int sm4[4];
  const int i = blockIdx.x * 256 + threadIdx.x;
  const int v = (i < N_NODES) ? cnt[i] : 0;
  if (i < N_NODES) dinv[i] = rsqrtf(deg[i]);  // deg >= 1 (self loop)
  int s = wredSumI(v);
  const int lane = threadIdx.x & 63, wid = threadIdx.x >> 6;
  if (lane == 0) sm4[wid] = s;
  __syncthreads();
  if (threadIdx.x == 0) csum[blockIdx.x] = sm4[0] + sm4[1] + sm4[2] + sm4[3];
}

__global__ __launch_bounds__(128) void k_scanB(const int* __restrict__ csum, int* __restrict__ cbase) {
  __shared__ int buf[128];
  const int tid = threadIdx.x;
  const int nchunk = (N_NODES + 255) / 256;
  const int v = (tid < nchunk) ? csum[tid] : 0;
  buf[tid] = v;
  __syncthreads();
#pragma unroll
  for (int d = 1; d < 128; d <<= 1) {
    const int u = (tid >= d) ? buf[tid - d] : 0;
    __syncthreads();
    buf[tid] += u;
    __syncthreads();
  }
  if (tid < nchunk) cbase[tid] = buf[tid] - v;  // exclusive
}

__global__ __launch_bounds__(256) void k_scanC(const int* __restrict__ cnt, const int* __restrict__ cbase,
                                               int* __restrict__ off, int* __restrict__ cursor) {
  __shared__ int wpart[4];
  const int tid = threadIdx.x, lane = tid & 63, wid = tid >> 6;
  const int i = blockIdx.x * 256 + tid;
  const int v = (i < N_NODES) ? cnt[i] : 0;
  int s = v;
#pragma unroll
  for (int d = 1; d < 64; d <<= 1) { const int u = __shfl_up(s, d, 64); if (lane >= d) s += u; }
  if (lane == 63) wpart[wid] = s;
  __syncthreads();
  int add = cbase[blockIdx.x];
#pragma unroll
  for (int wv = 0; wv < 4; ++wv) if (wv < wid) add += wpart[wv];
  if (i < N_NODES) { const int excl = add + (s - v); off[i] = excl; cursor[i] = excl; }
  if (i == N_NODES - 1) off[N_NODES] = E_EDGES;
}

__global__ __launch_bounds__(256) void k_norm_scatter(const int* __restrict__ ei, const float* __restrict__ ewv,
                                                      const float* __restrict__ dinv, int* __restrict__ cursor,
                                                      uint2* __restrict__ srcnrm) {
  const int e = blockIdx.x * 256 + threadIdx.x;
  const int r = ei[e], c = ei[E_EDGES + e];
  const float nm = dinv[r] * ewv[e] * dinv[c];
  const int pos = atomicAdd(&cursor[c], 1);
  srcnrm[pos] = make_uint2((unsigned int)r, __builtin_bit_cast(unsigned int, nm));
}

// ---------------- weight prep (+ fused deg/cnt init) ----------------
__global__ __launch_bounds__(256) void k_wprep(const float* __restrict__ tconv_w, const float* __restrict__ res_w,
                                               const float* __restrict__ gcn_w, unsigned int* __restrict__ Bf,
                                               float* __restrict__ deg, int* __restrict__ cnt) {
  const int gid = blockIdx.x * 256 + threadIdx.x;  // 96 blocks * 256 = 24576 exact
  if (gid < N_NODES) { deg[gid] = 1.0f; cnt[gid] = 0; }
  float v0, v1;
  if (gid < 12288) {
    const int reg = gid & 3, l = (gid >> 2) & 63, ct = (gid >> 8) & 7, ks = gid >> 11;
    const int o = ct * 16 + (l & 15);
    const int k0 = ks * 32 + ((l >> 4) & 3) * 8 + reg * 2;
    const int c0 = k0 & 63, tap0 = k0 >> 6;
    const int c1 = (k0 + 1) & 63, tap1 = (k0 + 1) >> 6;
    v0 = tconv_w[o * 192 + c0 * 3 + tap0];
    v1 = tconv_w[o * 192 + c1 * 3 + tap1];
  } else if (gid < 16384) {
    const int g = gid - 12288;
    const int reg = g & 3, l = (g >> 2) & 63, ct = (g >> 8) & 7, ks = g >> 11;
    const int o = ct * 16 + (l & 15);
    const int k0 = ks * 32 + ((l >> 4) & 3) * 8 + reg * 2;
    v0 = res_w[o * 64 + k0];
    v1 = res_w[o * 64 + k0 + 1];
  } else {
    const int g = gid - 16384;
    const int reg = g & 3, l = (g >> 2) & 63, ct = (g >> 8) & 7, ks = g >> 11;
    const int o = ct * 16 + (l & 15);
    const int k0 = ks * 32 + ((l >> 4) & 3) * 8 + reg * 2;
    v0 = gcn_w[o * 128 + k0];
    v1 = gcn_w[o * 128 + k0 + 1];
  }
  Bf[gid] = pack2(v0, v1);
}

// ---------------- FUSED node transform + GCN linear ----------------
// block = 16 nodes x 8 t = 128 output rows (row = nn*8 + t), 256 threads = 4 waves.
// Phase 1: stage x (all 8 t) into Xs with zero slots for t=-1, t=8 -> branch-free taps.
// Phase 2: conv+res MFMA (A from Xs) -> LN in-register -> As2 (bf16 transpose buffer in LDS)
// Phase 3: GCN GEMM (A from As2) -> int8 quant + bf16 xt store (k_xt's proven path).
#define XS_NODE 706   // bf16 units per node (10 slots * 68 + pad; 353 dwords == 1 mod 32)
#define XS_SLOT 68    // bf16 units per t-slot (64 ch + pad; 34 dwords == 2 mod 32)
#define AS2_STRIDE 136
__global__ __launch_bounds__(256, 2) void k_fuse(const float* __restrict__ x,
                                                 const float* __restrict__ tconv_b,
                                                 const float* __restrict__ ln_g, const float* __restrict__ ln_b,
                                                 const float* __restrict__ res_b,
                                                 const unsigned int* __restrict__ Bf,
                                                 unsigned short* __restrict__ xt,
                                                 unsigned char* __restrict__ xq,
                                                 float* __restrict__ qsc) {
  const int tid = threadIdx.x, lane = tid & 63, w = tid >> 6;
  const int l15 = lane & 15, lg = lane >> 4;
  const int n0 = blockIdx.x * 16;               // grid = 1250 exact

  __shared__ unsigned short Xs[16 * XS_NODE];   // 22592 B
  __shared__ unsigned short As2[128 * AS2_STRIDE];  // 34816 B
  __shared__ float psum[4][128], psq[4][128];   // 4096 B
  __shared__ float smu[128], srs[128];          // 1024 B
  __shared__ unsigned int nmax[16];

  if (tid < 16) nmax[tid] = 0u;

  // ---- phase 1: stage x -> Xs[node][slot=t+1][c] bf16; zero slots 0 and 9 ----
#pragma unroll
  for (int p = 0; p < 8; ++p) {
    const int chunk = p * 256 + tid;            // 2048 = 8t * 16n * 16 float4
    const int tq = chunk >> 8, nn = (chunk >> 4) & 15, c4 = chunk & 15;
    const float4 v = *(const float4*)(x + ((size_t)tq * N_NODES + n0 + nn) * C_IN + c4 * 4);
    uint2 pk; pk.x = pack2(v.x, v.y); pk.y = pack2(v.z, v.w);
    *(uint2*)&Xs[nn * XS_NODE + (tq + 1) * XS_SLOT + c4 * 4] = pk;
  }
#pragma unroll
  for (int p = 0; p < 3; ++p) {
    const int i = p * 256 + tid;                // 544 uint2 zero-writes (2 slots * 16n * 17)
    if (i < 544) {
      const int s = (i < 272) ? 0 : 9;
      const int r = (i < 272) ? i : i - 272;
      const int nn = r / 17, of = (r % 17) * 4;
      *(uint2*)&Xs[nn * XS_NODE + s * XS_SLOT + of] = make_uint2(0u, 0u);
    }
  }

  // ---- per-wave B fragments: conv + residual ----
  const uint4* Bf4 = (const uint4*)Bf;
  uint4 Bc[2][6], Br[2][2];
#pragma unroll
  for (int ct = 0; ct < 2; ++ct) {
    const int ctg = w * 2 + ct;
#pragma unroll
    for (int ks = 0; ks < 6; ++ks) Bc[ct][ks] = Bf4[(ks * 8 + ctg) * 64 + lane];
#pragma unroll
    for (int ks = 0; ks < 2; ++ks) Br[ct][ks] = Bf4[3072 + (ks * 8 + ctg) * 64 + lane];
  }
  float cb[2], rb[2], gv[2], bv[2];
#pragma unroll
  for (int ct = 0; ct < 2; ++ct) {
    const int col = w * 32 + ct * 16 + l15;
    cb[ct] = tconv_b[col]; rb[ct] = res_b[col]; gv[ct] = ln_g[col]; bv[ct] = ln_b[col];
  }
  __syncthreads();

  // ---- phase 2: conv + res MFMA over 8 row-tiles (rows = nn*8 + t, t = l15&7) ----
  f32x4 accC[8][2], accR[8][2];
#pragma unroll
  for (int rt = 0; rt < 8; ++rt)
#pragma unroll
    for (int ct = 0; ct < 2; ++ct) { accC[rt][ct] = (f32x4)0.f; accR[rt][ct] = (f32x4)0.f; }

#pragma unroll
  for (int ks = 0; ks < 6; ++ks) {
    bf16x8 af[8];
    const int slot = (l15 & 7) + (ks >> 1);   // t + tap (zero slots handle edges)
    const int koff = slot * XS_SLOT + (ks & 1) * 32 + lg * 8;
#pragma unroll
    for (int rt = 0; rt < 8; ++rt) {
      const int node = rt * 2 + (l15 >> 3);
      af[rt] = *(const bf16x8*)&Xs[node * XS_NODE + koff];
    }
#pragma unroll
    for (int rt = 0; rt < 8; ++rt)
#pragma unroll
      for (int ct = 0; ct < 2; ++ct)
        accC[rt][ct] = MFMA16(af[rt], __builtin_bit_cast(bf16x8, Bc[ct][ks]), accC[rt][ct]);
    if (ks == 2 || ks == 3) {                 // middle tap drives the 1x1 residual conv
#pragma unroll
      for (int rt = 0; rt < 8; ++rt)
#pragma unroll
        for (int ct = 0; ct < 2; ++ct)
          accR[rt][ct] = MFMA16(af[rt], __builtin_bit_cast(bf16x8, Br[ct][ks - 2]), accR[rt][ct]);
    }
  }

  // ---- LayerNorm stats (C-layout: row16 = lg*4+j, col = w*32+ct*16+l15) ----
#pragma unroll
  for (int rt = 0; rt < 8; ++rt) {
    float s[4], s2[4];
#pragma unroll
    for (int j = 0; j < 4; ++j) {
      const float h0 = accC[rt][0][j] + cb[0];
      const float h1 = accC[rt][1][j] + cb[1];
      accC[rt][0][j] = h0; accC[rt][1][j] = h1;
      s[j] = h0 + h1; s2[j] = h0 * h0 + h1 * h1;
    }
#pragma unroll
    for (int d = 1; d < 16; d <<= 1)
#pragma unroll
      for (int j = 0; j < 4; ++j) { s[j] += __shfl_xor(s[j], d, 64); s2[j] += __shfl_xor(s2[j], d, 64); }
    if (l15 == 0)
#pragma unroll
      for (int j = 0; j < 4; ++j) {
        psum[w][rt * 16 + lg * 4 + j] = s[j];
        psq[w][rt * 16 + lg * 4 + j] = s2[j];
      }
  }
  __syncthreads();
  if (tid < 128) {
    const float S  = psum[0][tid] + psum[1][tid] + psum[2][tid] + psum[3][tid];
    const float S2 = psq[0][tid] + psq[1][tid] + psq[2][tid] + psq[3][tid];
    const float mu = S * (1.f / 128.f);
    const float var = S2 * (1.f / 128.f) - mu * mu;
    smu[tid] = mu; srs[tid] = rsqrtf(var + 1e-5f);
  }
  __syncthreads();

  // ---- apply LN + ReLU + residual -> As2 (bf16) ----
#pragma unroll
  for (int rt = 0; rt < 8; ++rt)
#pragma unroll
    for (int j = 0; j < 4; ++j) {
      const int row = rt * 16 + lg * 4 + j;
      const float mu = smu[row], rs = srs[row];
#pragma unroll
      for (int ct = 0; ct < 2; ++ct) {
        float xc = (accC[rt][ct][j] - mu) * rs * gv[ct] + bv[ct];
        xc = fmaxf(xc, 0.f) + accR[rt][ct][j] + rb[ct];
        As2[row * AS2_STRIDE + w * 32 + ct * 16 + l15] = f2u(xc);
      }
    }
  __syncthreads();

  // ---- phase 3: GCN GEMM from As2 (k_xt's proven path) ----
  uint4 Bg[2][4];
#pragma unroll
  for (int ct = 0; ct < 2; ++ct)
#pragma unroll
    for (int ks = 0; ks < 4; ++ks) Bg[ct][ks] = Bf4[4096 + (ks * 8 + (w * 2 + ct)) * 64 + lane];

  f32x4 acc[8][2];
#pragma unroll
  for (int rt = 0; rt < 8; ++rt)
#pragma unroll
    for (int ct = 0; ct < 2; ++ct) acc[rt][ct] = (f32x4)0.f;

#pragma unroll
  for (int ks = 0; ks < 4; ++ks) {
    bf16x8 af[8];
#pragma unroll
    for (int rt = 0; rt < 8; ++rt)
      af[rt] = *(const bf16x8*)&As2[(rt * 16 + l15) * AS2_STRIDE + ks * 32 + lg * 8];
#pragma unroll
    for (int rt = 0; rt < 8; ++rt)
#pragma unroll
      for (int ct = 0; ct < 2; ++ct)
        acc[rt][ct] = MFMA16(af[rt], __builtin_bit_cast(bf16x8, Bg[ct][ks]), acc[rt][ct]);
  }

  // ---- per-node |max| for int8 scale ----
#pragma unroll
  for (int rt = 0; rt < 8; ++rt) {
    const int nn = rt * 2 + (lg >> 1);
    float m = 0.f;
#pragma unroll
    for (int ct = 0; ct < 2; ++ct)
#pragma unroll
      for (int j = 0; j < 4; ++j) m = fmaxf(m, fabsf(acc[rt][ct][j]));
    atomicMax(&nmax[nn], __builtin_bit_cast(unsigned int, m));  // >=0: uint order == float order
  }
  __syncthreads();
  if (tid < 16) qsc[n0 + tid] = __builtin_bit_cast(float, nmax[tid]) * (1.f / 127.f);

  // ---- store: row128 = rt*16+lg*4+j -> nn = rt*2+(lg>>1), t = (lg&1)*4 + j ----
  const int t0 = (lg & 1) * 4;
#pragma unroll
  for (int rt = 0; rt < 8; ++rt) {
    const int nn = rt * 2 + (lg >> 1);
    const size_t n = (size_t)(n0 + nn);
    const float mx = __builtin_bit_cast(float, nmax[nn]);
    const float inv = (mx > 0.f) ? 127.f / mx : 0.f;
#pragma unroll
    for (int ct = 0; ct < 2; ++ct) {
      const int col = w * 32 + ct * 16 + l15;
      uint2 pk;
      pk.x = pack2(acc[rt][ct][0], acc[rt][ct][1]);
      pk.y = pack2(acc[rt][ct][2], acc[rt][ct][3]);
      *(uint2*)(xt + (n * C_OUT + col) * T_STEPS + t0) = pk;
      unsigned int pk8 = 0;
#pragma unroll
      for (int j = 0; j < 4; ++j) {
        const int q = (int)rintf(acc[rt][ct][j] * inv) + 128;  // biased uint8
        pk8 |= ((unsigned int)q) << (8 * j);
      }
      *(unsigned int*)(xq + (n * C_OUT + col) * T_STEPS + t0) = pk8;
    }
  }
}

// ---------------- CSR aggregation + bias + ReLU -> out[T,N,128] ----------------
__global__ __launch_bounds__(256) void k_agg(const unsigned short* __restrict__ xt,
                                             const unsigned char* __restrict__ xq,
                                             const float* __restrict__ qsc,
                                             const uint2* __restrict__ srcnrm,
                                             const int* __restrict__ off, const float* __restrict__ dinv,
                                             const float* __restrict__ gcn_b, float* __restrict__ out) {
  const int tid = threadIdx.x, lane = tid & 63, w = tid >> 6;
  const int j = blockIdx.x * 4 + w;             // grid 5000 exact
  const int s = off[j], e = off[j + 1];
  const float d2 = dinv[j] * dinv[j];

  float acc[2][8];
#pragma unroll
  for (int h = 0; h < 2; ++h) {
    const uint4 q = *(const uint4*)(xt + ((size_t)j * C_OUT + h * 64 + lane) * T_STEPS);
    acc[h][0] = d2 * ulo(q.x); acc[h][1] = d2 * uhi(q.x);
    acc[h][2] = d2 * ulo(q.y); acc[h][3] = d2 * uhi(q.y);
    acc[h][4] = d2 * ulo(q.z); acc[h][5] = d2 * uhi(q.z);
    acc[h][6] = d2 * ulo(q.w); acc[h][7] = d2 * uhi(q.w);
  }

  float summul = 0.f;
  for (int k = s; k < e; ++k) {
    const uint2 sn = srcnrm[k];                  // wave-uniform
    const int r = (int)sn.x;
    const float mul = __builtin_bit_cast(float, sn.y) * qsc[r];
    summul += mul;
    const uint2 qa = *(const uint2*)(xq + ((size_t)r * C_OUT + lane) * T_STEPS);
    const uint2 qb = *(const uint2*)(xq + ((size_t)r * C_OUT + 64 + lane) * T_STEPS);
#pragma unroll
    for (int tt = 0; tt < 4; ++tt) {
      acc[0][tt]     = fmaf((float)((qa.x >> (8 * tt)) & 0xffu), mul, acc[0][tt]);
      acc[0][4 + tt] = fmaf((float)((qa.y >> (8 * tt)) & 0xffu), mul, acc[0][4 + tt]);
      acc[1][tt]     = fmaf((float)((qb.x >> (8 * tt)) & 0xffu), mul, acc[1][tt]);
      acc[1][4 + tt] = fmaf((float)((qb.y >> (8 * tt)) & 0xffu), mul, acc[1][4 + tt]);
    }
  }

  const float corr = 128.f * summul;             // biased-uint8 correction
  const float b0 = gcn_b[lane], b1 = gcn_b[64 + lane];
#pragma unroll
  for (int h = 0; h < 2; ++h) {
    const float bo = h ? b1 : b0;
#pragma unroll
    for (int t = 0; t < 8; ++t) {
      const float v = acc[h][t] - corr + bo;
      out[((size_t)t * N_NODES + j) * C_OUT + h * 64 + lane] = fmaxf(v, 0.f);
    }
  }
}

// ---------------- host ----------------
extern "C" void kernel_launch(void* const* d_in, const int* in_sizes, int n_in,
                              void* d_out, int out_size, void* d_ws, size_t ws_size,
                              hipStream_t stream) {
  (void)in_sizes; (void)n_in; (void)out_size; (void)ws_size;
  const float* x       = (const float*)d_in[0];
  const int*   ei      = (const int*)d_in[1];
  const float* ewt     = (const float*)d_in[2];
  const float* tconv_w = (const float*)d_in[3];
  const float* tconv_b = (const float*)d_in[4];
  const float* ln_g    = (const float*)d_in[5];
  const float* ln_b    = (const float*)d_in[6];
  const float* res_w   = (const float*)d_in[7];
  const float* res_b   = (const float*)d_in[8];
  const float* gcn_w   = (const float*)d_in[9];
  const float* gcn_b   = (const float*)d_in[10];
  float* out = (float*)d_out;

  // workspace carve (~65 MB)
  unsigned short* xt = (unsigned short*)d_ws;                       // N*128*8 bf16 = 40.96 MB
  unsigned char*  xq = (unsigned char*)(xt + (size_t)N_NODES * C_OUT * T_STEPS);  // N*128*8 u8 = 20.48 MB
  float* qsc  = (float*)(xq + (size_t)N_NODES * C_OUT * T_STEPS);   // N
  unsigned int* Bf = (unsigned int*)(qsc + N_NODES);                // 24576 u32
  float* ewv   = (float*)(Bf + 24576);                              // E
  float* deg   = ewv + E_EDGES;                                     // N
  float* dinv  = deg + N_NODES;                                     // N
  float* pm    = dinv + N_NODES;                                    // 256
  float* ps    = pm + 256;                                          // 256
  int*   cnt    = (int*)(ps + 256);                                 // N
  int*   off    = cnt + N_NODES;                                    // N+1
  int*   cursor = off + N_NODES + 1;                                // N
  int*   csum   = cursor + N_NODES;                                 // 128
  int*   cbase  = csum + 128;                                       // 128
  uint2* srcnrm = (uint2*)(((size_t)(cbase + 128) + 15) & ~(size_t)15);  // E * 8B

  const int nblk = (N_NODES + 255) / 256;                           // 79
  const int eblk = E_EDGES / 256;                                   // 625 exact

  k_wprep<<<96, 256, 0, stream>>>(tconv_w, res_w, gcn_w, Bf, deg, cnt);
  k_pmax<<<256, 256, 0, stream>>>(ewt, pm);
  k_sumexp<<<256, 256, 0, stream>>>(ewt, pm, ps);
  k_edge<<<eblk, 256, 0, stream>>>(ewt, ei, pm, ps, ewv, deg, cnt);
  k_scanA<<<nblk, 256, 0, stream>>>(cnt, deg, dinv, csum);
  k_scanB<<<1, 128, 0, stream>>>(csum, cbase);
  k_scanC<<<nblk, 256, 0, stream>>>(cnt, cbase, off, cursor);
  k_norm_scatter<<<eblk, 256, 0, stream>>>(ei, ewv, dinv, cursor, srcnrm);

  k_fuse<<<1250, 256, 0, stream>>>(x, tconv_b, ln_g, ln_b, res_b, Bf, xt, xq, qsc);
  k_agg<<<N_NODES / 4, 256, 0, stream>>>(xt, xq, qsc, srcnrm, off, dinv, gcn_b, out);
}